// Round 6
// baseline (545.585 us; speedup 1.0000x reference)
//
#include <hip/hip_runtime.h>
#include <hip/hip_bf16.h>
#include <cstdint>

typedef __attribute__((ext_vector_type(8))) short short8;
typedef __attribute__((ext_vector_type(4))) float f32x4;
typedef unsigned short u16;

__device__ __forceinline__ float b2f(u16 u) {
  union { unsigned int i; float f; } v; v.i = ((unsigned int)u) << 16; return v.f;
}
// hardware RNE f32->bf16 (v_cvt on gfx950)
__device__ __forceinline__ u16 f2b(float f) {
  __hip_bfloat16 h = __float2bfloat16(f);
  union { __hip_bfloat16 h; u16 u; } v; v.h = h; return v.u;
}
__device__ __forceinline__ float silu_f(float x) { return x / (1.0f + __expf(-x)); }

__device__ __forceinline__ float loadF(const void* p, long i, int isf32) {
  if (isf32) return ((const float*)p)[i];
  return b2f(((const u16*)p)[i]);
}

// per-thread dtype sniff: f32 data viewed as u16 has ~25% of even indices with
// bf16-exponent-field >= 0xC0; genuine bf16 N(0,1)/uniform has none.
__device__ __forceinline__ int detect1(const void* p, int n) {
  const u16* q = (const u16*)p;
  int m = n < 512 ? n : 512;
  int h = 0;
  for (int k = 0; k < m; ++k) h += (((q[k] >> 7) & 0xffu) >= 0xC0u) ? 1 : 0;
  return h >= 2;
}

struct Ptrs { const void* p[20]; };

// f32 prepped-weight layout (float offsets)
#define FW_NW1 0
#define FW_NW2 4096
#define FW_UW1 8192
#define FW_UW2 12288
#define FW_EW1 16384
#define FW_NB1 16768
#define FW_NB2 16832
#define FW_UB1 16896
#define FW_UB2 16960
#define FW_EB1 17024
#define FW_EB2 17088
#define FW_MB1 17152
#define FW_MB2 17216
#define FW_TOTAL 17280

// bf16 transposed image layout (u16 offsets)
#define IMG_EW2 0
#define IMG_MW1 4608
#define IMG_MW2 13312
#define IMG_TOTAL 17920

#define PREP_BLOCKS 138   // ceil((IMG_TOTAL+FW_TOTAL)/256)
#define HIST_BLOCKS 1024

// ---------------------------------------------------------------------------
// Fused kernel A: blocks [0,PREP_BLOCKS) = weight prep (self-detecting dtype),
//                 blocks [PREP_BLOCKS, ..) = target histogram.
// ---------------------------------------------------------------------------
__global__ __launch_bounds__(256) void prep_hist_k(Ptrs a, u16* img, float* fw,
                                                   const int* __restrict__ eidx,
                                                   int* __restrict__ cnt,
                                                   long E, int G) {
  const int t = threadIdx.x;
  if ((int)blockIdx.x >= PREP_BLOCKS) {
    long i = (long)(blockIdx.x - PREP_BLOCKS) * 256 + t;
    const long stride = (long)HIST_BLOCKS * 256;
    for (; i < E; i += stride) {
      int tg = eidx[E + i];
      if (tg >= 0 && tg < G) atomicAdd(&cnt[tg], 1);
    }
    return;
  }
  int i = blockIdx.x * 256 + t;
  if (i < IMG_TOTAL) {
    const void* bp; int n; long si; bool real;
    if (i < IMG_MW1) { int nn = i / 72, k = i % 72; bp = a.p[10]; n = 4096; real = k < 64; si = (long)k * 64 + nn; }
    else if (i < IMG_MW2) { int t2 = i - IMG_MW1; int nn = t2 / 136, k = t2 % 136; bp = a.p[12]; n = 8192; real = k < 128; si = (long)k * 64 + nn; }
    else { int t2 = i - IMG_MW2; int nn = t2 / 72, k = t2 % 72; bp = a.p[14]; n = 4096; real = k < 64; si = (long)k * 64 + nn; }
    u16 val = 0;
    if (real) { int isf = detect1(bp, n); val = f2b(loadF(bp, si, isf)); }
    img[i] = val;
  } else if (i < IMG_TOTAL + FW_TOTAL) {
    int j = i - IMG_TOTAL;
    const void* bp; int n; long si;
    if (j < 4096)       { bp = a.p[4];  n = 4096; si = j; }
    else if (j < 8192)  { bp = a.p[6];  n = 4096; si = j - 4096; }
    else if (j < 12288) { bp = a.p[16]; n = 4096; si = j - 8192; }
    else if (j < 16384) { bp = a.p[18]; n = 4096; si = j - 12288; }
    else if (j < 16768) { bp = a.p[8];  n = 384;  si = j - 16384; }
    else {
      int b = j - 16768; int seg = b >> 6; si = b & 63; n = 64;
      switch (seg) {
        case 0: bp = a.p[5];  break;
        case 1: bp = a.p[7];  break;
        case 2: bp = a.p[17]; break;
        case 3: bp = a.p[19]; break;
        case 4: bp = a.p[9];  break;
        case 5: bp = a.p[11]; break;
        case 6: bp = a.p[13]; break;
        default: bp = a.p[15]; break;
      }
    }
    int isf = detect1(bp, n);
    fw[j] = loadF(bp, si, isf);
  }
}

// ---------------------------------------------------------------------------
// Fused kernel B: blocks [0,nodeBlocks) = node MLP (self-detecting dtype),
//                 blocks [nodeBlocks, +NB2) = per-256-chunk exclusive scan.
// ---------------------------------------------------------------------------
__global__ __launch_bounds__(256) void node_scan_k(
    const void* x, const float* __restrict__ fw, u16* __restrict__ out, int nrows,
    const int* __restrict__ cnt, int* __restrict__ cursor, int* __restrict__ bsum,
    int G, int nodeBlocks)
{
  __shared__ float xs[64][68];
  __shared__ float w1s[64][68];
  __shared__ float w2s[64][68];
  __shared__ float b1s[64];
  __shared__ float b2s[64];
  __shared__ int sd2[256];
  __shared__ int xdet;
  const int t = threadIdx.x;

  if ((int)blockIdx.x >= nodeBlocks) {
    // ---- scan part ----
    int b2 = blockIdx.x - nodeBlocks;
    int i = b2 * 256 + t;
    int v = (i < G) ? cnt[i] : 0;
    sd2[t] = v;
    __syncthreads();
    for (int off = 1; off < 256; off <<= 1) {
      int x2 = (t >= off) ? sd2[t - off] : 0;
      __syncthreads();
      sd2[t] += x2;
      __syncthreads();
    }
    if (i < G) cursor[i] = sd2[t] - v;
    if (t == 255) bsum[b2] = sd2[255];
    return;
  }
  // ---- node MLP part ----
  if (t == 0) xdet = 0;
  __syncthreads();
  {
    const u16* q = (const u16*)x;
    int c = 0;
    for (int i = t; i < 4096; i += 256) c += (((q[i] >> 7) & 0xffu) >= 0xC0u) ? 1 : 0;
    if (c) atomicAdd(&xdet, c);
  }
  const long rbase = (long)blockIdx.x * 64;
  for (int i = t; i < 4096; i += 256) {
    int k = i >> 6, cc = i & 63;
    w1s[k][cc] = fw[FW_NW1 + i];
    w2s[k][cc] = fw[FW_NW2 + i];
  }
  if (t < 64) { b1s[t] = fw[FW_NB1 + t]; b2s[t] = fw[FW_NB2 + t]; }
  __syncthreads();
  const int xf = xdet >= 2;
  {
    int row = t >> 2, ch = t & 3;
    long rg = rbase + row;
    if (rg < nrows) {
      if (xf) {
        const float* xp = (const float*)x + rg * 64 + ch * 16;
#pragma unroll
        for (int m = 0; m < 16; ++m) xs[row][ch * 16 + m] = xp[m];
      } else {
        const u16* xp = (const u16*)x + rg * 64 + ch * 16;
#pragma unroll
        for (int m = 0; m < 16; ++m) xs[row][ch * 16 + m] = b2f(xp[m]);
      }
    } else {
#pragma unroll
      for (int m = 0; m < 16; ++m) xs[row][ch * 16 + m] = 0.f;
    }
  }
  __syncthreads();
  const int r0 = (t >> 4) * 4, c0 = (t & 15) * 4;
  float acc[4][4];
#pragma unroll
  for (int i = 0; i < 4; ++i)
#pragma unroll
    for (int j = 0; j < 4; ++j) acc[i][j] = b1s[c0 + j];
  for (int k = 0; k < 64; ++k) {
    float w0 = w1s[k][c0], w1v = w1s[k][c0 + 1], w2v = w1s[k][c0 + 2], w3v = w1s[k][c0 + 3];
#pragma unroll
    for (int i = 0; i < 4; ++i) {
      float av = xs[r0 + i][k];
      acc[i][0] = fmaf(av, w0, acc[i][0]);
      acc[i][1] = fmaf(av, w1v, acc[i][1]);
      acc[i][2] = fmaf(av, w2v, acc[i][2]);
      acc[i][3] = fmaf(av, w3v, acc[i][3]);
    }
  }
  __syncthreads();
#pragma unroll
  for (int i = 0; i < 4; ++i)
#pragma unroll
    for (int j = 0; j < 4; ++j) xs[r0 + i][c0 + j] = silu_f(acc[i][j]);
  __syncthreads();
  float acc2[4][4];
#pragma unroll
  for (int i = 0; i < 4; ++i)
#pragma unroll
    for (int j = 0; j < 4; ++j) acc2[i][j] = b2s[c0 + j];
  for (int k = 0; k < 64; ++k) {
    float w0 = w2s[k][c0], w1v = w2s[k][c0 + 1], w2v = w2s[k][c0 + 2], w3v = w2s[k][c0 + 3];
#pragma unroll
    for (int i = 0; i < 4; ++i) {
      float av = xs[r0 + i][k];
      acc2[i][0] = fmaf(av, w0, acc2[i][0]);
      acc2[i][1] = fmaf(av, w1v, acc2[i][1]);
      acc2[i][2] = fmaf(av, w2v, acc2[i][2]);
      acc2[i][3] = fmaf(av, w3v, acc2[i][3]);
    }
  }
#pragma unroll
  for (int i = 0; i < 4; ++i) {
    long rg = rbase + r0 + i;
    if (rg < nrows) {
#pragma unroll
      for (int j = 0; j < 4; ++j) out[rg * 64 + c0 + j] = f2b(acc2[i][j]);
    }
  }
}

// ---------------------------------------------------------------------------
// Kernel C: scatter into sorted order; inline top-level scan of bsum (<=256).
// pack: src (17 bits) | tgt<<17 (15 bits)
// ---------------------------------------------------------------------------
__global__ __launch_bounds__(256) void scat_k(const int* __restrict__ eidx,
                                              int* __restrict__ cursor,
                                              const int* __restrict__ bsum,
                                              unsigned int* __restrict__ pkS,
                                              int* __restrict__ evp,
                                              long E, int G, int NB2) {
  __shared__ int bo[256];
  const int t = threadIdx.x;
  int v = (t < NB2) ? bsum[t] : 0;
  bo[t] = v;
  __syncthreads();
  for (int off = 1; off < 256; off <<= 1) {
    int x2 = (t >= off) ? bo[t - off] : 0;
    __syncthreads();
    bo[t] += x2;
    __syncthreads();
  }
  if (blockIdx.x == 0 && t == 0) *evp = bo[NB2 - 1];
  int excl = bo[t] - v;
  __syncthreads();
  bo[t] = excl;
  __syncthreads();
  long i = (long)blockIdx.x * 256 + t;
  const long stride = (long)gridDim.x * 256;
  for (; i < E; i += stride) {
    int tg = eidx[E + i];
    if (tg >= 0 && tg < G) {
      int s = eidx[i];
      int p = atomicAdd(&cursor[tg], 1) + bo[tg >> 8];
      pkS[p] = (unsigned int)s | ((unsigned int)tg << 17);
    }
  }
}

// ---------------------------------------------------------------------------
// Kernel D: edge pipeline over SORTED edges, software-pipelined gathers.
// Tile k+1's pkS/geometry/h_node prefetched into REGISTERS during tile k's
// MFMA stages (register loads don't drain at s_barrier). 6 barriers/tile.
// ---------------------------------------------------------------------------
#define ETILES 4

__global__ __launch_bounds__(256, 5) void edge_kernel(
    const void* node_pos, const void* grid_pos, const void* orient,
    const unsigned int* __restrict__ pkS, const int* __restrict__ evp,
    const u16* __restrict__ h_node, const u16* __restrict__ img,
    const float* __restrict__ fw,
    float* __restrict__ sums, int G)
{
  __shared__ __align__(16) u16 hA[64][136];    // msg_in; after S3 reused as msgf
  __shared__ __align__(16) u16 ef1[64][72];
  __shared__ float eaf[64][6];
  __shared__ float w1e[6][64];
  __shared__ float biasE[4][64];
  __shared__ int tgt_s[64];
  __shared__ int det[3];
  float (*msgf)[66] = (float (*)[66])&hA[0][0];

  const int t = threadIdx.x;
  // ---- self-detect dtypes of node_pos/grid_pos/orient ----
  if (t < 3) det[t] = 0;
  __syncthreads();
  {
    int grp = t >> 6;
    if (grp < 3) {
      const u16* q = (const u16*)(grp == 0 ? node_pos : grp == 1 ? grid_pos : orient);
      int c = 0, l = t & 63;
      for (int i = l; i < 2048; i += 64) c += (((q[i] >> 7) & 0xffu) >= 0xC0u) ? 1 : 0;
      if (c) atomicAdd(&det[grp], c);
    }
  }
  for (int i = t; i < 384; i += 256) w1e[i / 64][i % 64] = fw[FW_EW1 + i];
  { int seg = t >> 6, cc = t & 63; biasE[seg][cc] = fw[FW_EB1 + seg * 64 + cc]; }
  __syncthreads();
  const int pf = det[0] >= 2, gf = det[1] >= 2, of = det[2] >= 2;
  const int Ev = *evp;

  const int lane = t & 63, w = t >> 6;
  const int q = lane >> 4, c = lane & 15;
  const int m0 = w * 16;
  const u16* wE2 = img + IMG_EW2;
  const u16* wM1 = img + IMG_MW1;
  const u16* wM2 = img + IMG_MW2;
  const f32x4 z = {0.f, 0.f, 0.f, 0.f};

  // pipeline registers
  short8 hv0, hv1;
  int my_tg = -1;
  float g0 = 0, g1 = 0, g2 = 0, g3 = 0, g4 = 0, g5 = 0;

  auto prefetch = [&](long base) {
    {  // h_node: all threads, edge base+(t>>2), 16B chunk (t&3)
      long eg = base + (t >> 2);
      int s = 0;
      if (eg < Ev) s = (int)(pkS[eg] & 0x1FFFFu);
      const u16* hp = h_node + (long)s * 64 + (t & 3) * 16;
      hv0 = *(const short8*)hp;
      hv1 = *(const short8*)(hp + 8);
    }
    if (t < 64) {  // geometry for edge base+t
      long eg = base + t;
      int s = 0, tg = -1;
      if (eg < Ev) { unsigned int pk = pkS[eg]; s = (int)(pk & 0x1FFFFu); tg = (int)(pk >> 17); }
      my_tg = tg;
      int tgc = (tg >= 0) ? tg : 0;
      float ps[3], rel[3], tr[3];
#pragma unroll
      for (int i = 0; i < 3; ++i) {
        ps[i] = loadF(node_pos, (long)s * 3 + i, pf);
        rel[i] = loadF(grid_pos, (long)tgc * 3 + i, gf) - ps[i];
      }
#pragma unroll
      for (int j = 0; j < 3; ++j) tr[j] = 0.f;
#pragma unroll
      for (int i = 0; i < 3; ++i)
#pragma unroll
        for (int j = 0; j < 3; ++j)
          tr[j] = fmaf(rel[i], loadF(orient, (long)s * 9 + i * 3 + j, of), tr[j]);
      g0 = ps[0]; g1 = ps[1]; g2 = ps[2]; g3 = tr[0]; g4 = tr[1]; g5 = tr[2];
    }
  };

  const long blk0 = (long)blockIdx.x * ETILES * 64;
  prefetch(blk0);

  for (int tile = 0; tile < ETILES; ++tile) {
    long base = blk0 + (long)tile * 64;
    if (base >= Ev) break;
    __syncthreads();  // previous tile's reduce done; LDS reusable
    // commit prefetched registers to LDS
    if (t < 64) {
      tgt_s[t] = my_tg;
      eaf[t][0] = g0; eaf[t][1] = g1; eaf[t][2] = g2;
      eaf[t][3] = g3; eaf[t][4] = g4; eaf[t][5] = g5;
    }
    {
      int e = t >> 2, ch = t & 3;
      *(short8*)&hA[e][ch * 16] = hv0;
      *(short8*)&hA[e][ch * 16 + 8] = hv1;
    }
    // issue next tile's gathers now; they stay in flight through S1..S4
    prefetch(base + 64);
    __syncthreads();  // LDS committed

    // S1: edge MLP layer1 (K=6) f32 VALU -> silu -> ef1 (bf16)
    {
      int e = t >> 2, c0 = (t & 3) * 16;
      float a0 = eaf[e][0], a1 = eaf[e][1], a2 = eaf[e][2];
      float a3 = eaf[e][3], a4 = eaf[e][4], a5 = eaf[e][5];
      __align__(16) u16 tmp[16];
#pragma unroll
      for (int j = 0; j < 16; ++j) {
        int cc = c0 + j;
        float acc = biasE[0][cc];
        acc = fmaf(a0, w1e[0][cc], acc);
        acc = fmaf(a1, w1e[1][cc], acc);
        acc = fmaf(a2, w1e[2][cc], acc);
        acc = fmaf(a3, w1e[3][cc], acc);
        acc = fmaf(a4, w1e[4][cc], acc);
        acc = fmaf(a5, w1e[5][cc], acc);
        tmp[j] = f2b(silu_f(acc));
      }
      *(short8*)&ef1[e][c0] = *(const short8*)tmp;
      *(short8*)&ef1[e][c0 + 8] = *(const short8*)(tmp + 8);
    }
    __syncthreads();
    // S2: edge MLP layer2 (K=64) -> hA cols 64..127
    {
      short8 a0 = *(const short8*)&ef1[m0 + c][q * 8];
      short8 a1 = *(const short8*)&ef1[m0 + c][32 + q * 8];
#pragma unroll
      for (int nt = 0; nt < 4; ++nt) {
        short8 b0 = *(const short8*)&wE2[(nt * 16 + c) * 72 + q * 8];
        short8 b1v = *(const short8*)&wE2[(nt * 16 + c) * 72 + 32 + q * 8];
        f32x4 acc = __builtin_amdgcn_mfma_f32_16x16x32_bf16(a0, b0, z, 0, 0, 0);
        acc = __builtin_amdgcn_mfma_f32_16x16x32_bf16(a1, b1v, acc, 0, 0, 0);
#pragma unroll
        for (int r = 0; r < 4; ++r) {
          int row = m0 + q * 4 + r, col = nt * 16 + c;
          hA[row][64 + col] = f2b(acc[r] + biasE[1][col]);
        }
      }
    }
    __syncthreads();
    // S3: msg MLP layer1 (K=128) -> silu -> ef1
    {
      short8 a0 = *(const short8*)&hA[m0 + c][q * 8];
      short8 a1 = *(const short8*)&hA[m0 + c][32 + q * 8];
      short8 a2 = *(const short8*)&hA[m0 + c][64 + q * 8];
      short8 a3 = *(const short8*)&hA[m0 + c][96 + q * 8];
#pragma unroll
      for (int nt = 0; nt < 4; ++nt) {
        const u16* wp = &wM1[(nt * 16 + c) * 136];
        f32x4 acc = __builtin_amdgcn_mfma_f32_16x16x32_bf16(a0, *(const short8*)(wp + q * 8), z, 0, 0, 0);
        acc = __builtin_amdgcn_mfma_f32_16x16x32_bf16(a1, *(const short8*)(wp + 32 + q * 8), acc, 0, 0, 0);
        acc = __builtin_amdgcn_mfma_f32_16x16x32_bf16(a2, *(const short8*)(wp + 64 + q * 8), acc, 0, 0, 0);
        acc = __builtin_amdgcn_mfma_f32_16x16x32_bf16(a3, *(const short8*)(wp + 96 + q * 8), acc, 0, 0, 0);
#pragma unroll
        for (int r = 0; r < 4; ++r) {
          int row = m0 + q * 4 + r, col = nt * 16 + c;
          ef1[row][col] = f2b(silu_f(acc[r] + biasE[2][col]));
        }
      }
    }
    __syncthreads();  // hA dead from here: msgf overlays it
    // S4: msg MLP layer2 (K=64) -> msgf (f32, +bias)
    {
      short8 a0 = *(const short8*)&ef1[m0 + c][q * 8];
      short8 a1 = *(const short8*)&ef1[m0 + c][32 + q * 8];
#pragma unroll
      for (int nt = 0; nt < 4; ++nt) {
        short8 b0 = *(const short8*)&wM2[(nt * 16 + c) * 72 + q * 8];
        short8 b1v = *(const short8*)&wM2[(nt * 16 + c) * 72 + 32 + q * 8];
        f32x4 acc = __builtin_amdgcn_mfma_f32_16x16x32_bf16(a0, b0, z, 0, 0, 0);
        acc = __builtin_amdgcn_mfma_f32_16x16x32_bf16(a1, b1v, acc, 0, 0, 0);
#pragma unroll
        for (int r = 0; r < 4; ++r) {
          int row = m0 + q * 4 + r, col = nt * 16 + c;
          msgf[row][col] = acc[r] + biasE[3][col];
        }
      }
    }
    __syncthreads();
    // Run-reduction: interior runs plain-store, boundary runs atomicAdd.
    {
      int col = lane;
      int r0 = w * 16;
      int cur = tgt_s[r0];
      float run = msgf[r0][col];
      bool lopen = (r0 == 0) ? true : (tgt_s[r0 - 1] == cur);
#pragma unroll
      for (int r2 = 1; r2 < 16; ++r2) {
        int r = r0 + r2;
        int tg = tgt_s[r];
        float v = msgf[r][col];
        if (tg == cur) {
          run += v;
        } else {
          if (cur >= 0) {
            if (lopen) unsafeAtomicAdd(&sums[(long)cur * 64 + col], run);
            else sums[(long)cur * 64 + col] = run;
          }
          cur = tg; run = v; lopen = false;
        }
      }
      bool ropen = (r0 + 16 >= 64) ? true : (tgt_s[r0 + 16] == cur);
      if (cur >= 0) {
        if (lopen || ropen) unsafeAtomicAdd(&sums[(long)cur * 64 + col], run);
        else sums[(long)cur * 64 + col] = run;
      }
    }
  }
}

// ---------------------------------------------------------------------------
// Kernel E: scatter-mean (int counts) + update MLP (f32) -> f32 out [G,64]
// ---------------------------------------------------------------------------
__global__ __launch_bounds__(256) void upd_mlp(
    const float* __restrict__ sums, const int* __restrict__ cnt,
    const float* __restrict__ fw, float* __restrict__ out, int nrows)
{
  __shared__ float xs[64][68];
  __shared__ float w1s[64][68];
  __shared__ float w2s[64][68];
  __shared__ float b1s[64];
  __shared__ float b2s[64];
  const int t = threadIdx.x;
  const long rbase = (long)blockIdx.x * 64;
  for (int i = t; i < 4096; i += 256) {
    int k = i >> 6, cc = i & 63;
    w1s[k][cc] = fw[FW_UW1 + i];
    w2s[k][cc] = fw[FW_UW2 + i];
  }
  if (t < 64) { b1s[t] = fw[FW_UB1 + t]; b2s[t] = fw[FW_UB2 + t]; }
  {
    int row = t >> 2, ch = t & 3;
    long rg = rbase + row;
    if (rg < nrows) {
      float inv = 1.0f / fmaxf((float)cnt[rg], 1.0f);
      const float* p = sums + rg * 64 + ch * 16;
#pragma unroll
      for (int m = 0; m < 16; ++m) xs[row][ch * 16 + m] = p[m] * inv;
    } else {
#pragma unroll
      for (int m = 0; m < 16; ++m) xs[row][ch * 16 + m] = 0.f;
    }
  }
  __syncthreads();
  const int r0 = (t >> 4) * 4, c0 = (t & 15) * 4;
  float acc[4][4];
#pragma unroll
  for (int i = 0; i < 4; ++i)
#pragma unroll
    for (int j = 0; j < 4; ++j) acc[i][j] = b1s[c0 + j];
  for (int k = 0; k < 64; ++k) {
    float w0 = w1s[k][c0], w1v = w1s[k][c0 + 1], w2v = w1s[k][c0 + 2], w3v = w1s[k][c0 + 3];
#pragma unroll
    for (int i = 0; i < 4; ++i) {
      float av = xs[r0 + i][k];
      acc[i][0] = fmaf(av, w0, acc[i][0]);
      acc[i][1] = fmaf(av, w1v, acc[i][1]);
      acc[i][2] = fmaf(av, w2v, acc[i][2]);
      acc[i][3] = fmaf(av, w3v, acc[i][3]);
    }
  }
  __syncthreads();
#pragma unroll
  for (int i = 0; i < 4; ++i)
#pragma unroll
    for (int j = 0; j < 4; ++j) xs[r0 + i][c0 + j] = silu_f(acc[i][j]);
  __syncthreads();
  float acc2[4][4];
#pragma unroll
  for (int i = 0; i < 4; ++i)
#pragma unroll
    for (int j = 0; j < 4; ++j) acc2[i][j] = b2s[c0 + j];
  for (int k = 0; k < 64; ++k) {
    float w0 = w2s[k][c0], w1v = w2s[k][c0 + 1], w2v = w2s[k][c0 + 2], w3v = w2s[k][c0 + 3];
#pragma unroll
    for (int i = 0; i < 4; ++i) {
      float av = xs[r0 + i][k];
      acc2[i][0] = fmaf(av, w0, acc2[i][0]);
      acc2[i][1] = fmaf(av, w1v, acc2[i][1]);
      acc2[i][2] = fmaf(av, w2v, acc2[i][2]);
      acc2[i][3] = fmaf(av, w3v, acc2[i][3]);
    }
  }
#pragma unroll
  for (int i = 0; i < 4; ++i) {
    long rg = rbase + r0 + i;
    if (rg < nrows) {
#pragma unroll
      for (int j = 0; j < 4; ++j) out[rg * 64 + c0 + j] = acc2[i][j];
    }
  }
}

// ---------------------------------------------------------------------------
extern "C" void kernel_launch(void* const* d_in, const int* in_sizes, int n_in,
                              void* d_out, int out_size, void* d_ws, size_t ws_size,
                              hipStream_t stream) {
  const int N = in_sizes[1] / 3;
  const int G = in_sizes[2] / 3;
  const long E = (long)in_sizes[4] / 2;
  const int NB2 = (G + 255) / 256;          // <=256 required (G<=65536)
  const int nodeBlocks = (N + 63) / 64;

  char* ws = (char*)d_ws;
  float* sums = (float*)ws;
  size_t off = (size_t)G * 256;
  int* cnt = (int*)(ws + off);     off += (size_t)G * 4;
  int* cursor = (int*)(ws + off);  off += (size_t)G * 4;
  int* bsum = (int*)(ws + off);    off += 1024;
  int* evp = (int*)(ws + off);     off += 256;
  unsigned int* pkS = (unsigned int*)(ws + off); off += (size_t)E * 4;
  u16* h_node = (u16*)(ws + off);  off += (size_t)N * 128;
  u16* img = (u16*)(ws + off);     off += (size_t)IMG_TOTAL * 2;
  float* fw = (float*)(ws + off);

  // zero sums + cnt (ws poisoned 0xAA before every timed launch)
  hipMemsetAsync(ws, 0, (size_t)G * 260, stream);

  Ptrs a;
  const int map[20] = {0,1,2,3, 5,6,7,8, 9,10,11,12, 13,14,15,16, 17,18,19,20};
  for (int i = 0; i < 20; ++i) a.p[i] = d_in[map[i]];

  prep_hist_k<<<PREP_BLOCKS + HIST_BLOCKS, 256, 0, stream>>>(
      a, img, fw, (const int*)d_in[4], cnt, E, G);
  node_scan_k<<<nodeBlocks + NB2, 256, 0, stream>>>(
      d_in[0], fw, h_node, N, cnt, cursor, bsum, G, nodeBlocks);
  scat_k<<<1024, 256, 0, stream>>>((const int*)d_in[4], cursor, bsum, pkS, evp, E, G, NB2);
  edge_kernel<<<(int)((E + ETILES * 64 - 1) / (ETILES * 64)), 256, 0, stream>>>(
      d_in[1], d_in[2], d_in[3], pkS, evp, h_node, img, fw, sums, G);
  upd_mlp<<<(G + 63) / 64, 256, 0, stream>>>(sums, cnt, fw, (float*)d_out, G);
}

// Round 7
// 494.368 us; speedup vs baseline: 1.1036x; 1.1036x over previous
//
#include <hip/hip_runtime.h>
#include <hip/hip_bf16.h>
#include <cstdint>

typedef __attribute__((ext_vector_type(8))) short short8;
typedef __attribute__((ext_vector_type(4))) float f32x4;
typedef unsigned short u16;

__device__ __forceinline__ float b2f(u16 u) {
  union { unsigned int i; float f; } v; v.i = ((unsigned int)u) << 16; return v.f;
}
// hardware RNE f32->bf16
__device__ __forceinline__ u16 f2b(float f) {
  __hip_bfloat16 h = __float2bfloat16(f);
  union { __hip_bfloat16 h; u16 u; } v; v.h = h; return v.u;
}
__device__ __forceinline__ float silu_f(float x) { return x / (1.0f + __expf(-x)); }

__device__ __forceinline__ float loadF(const void* p, long i, int isf32) {
  if (isf32) return ((const float*)p)[i];
  return b2f(((const u16*)p)[i]);
}

// per-thread dtype sniff: f32 viewed as u16 -> ~25% of low-halves have
// bf16-exponent-field >= 0xC0; genuine bf16 N(0,1)/uniform data has none.
__device__ __forceinline__ int detect1(const void* p, int n) {
  const u16* q = (const u16*)p;
  int m = n < 512 ? n : 512;
  int h = 0;
  for (int k = 0; k < m; ++k) h += (((q[k] >> 7) & 0xffu) >= 0xC0u) ? 1 : 0;
  return h >= 2;
}

struct Ptrs { const void* p[20]; };

// f32 prepped-weight layout (float offsets)
#define FW_NW1 0
#define FW_NW2 4096
#define FW_UW1 8192
#define FW_UW2 12288
#define FW_EW1 16384
#define FW_NB1 16768
#define FW_NB2 16832
#define FW_UB1 16896
#define FW_UB2 16960
#define FW_EB1 17024
#define FW_EB2 17088
#define FW_MB1 17152
#define FW_MB2 17216
#define FW_TOTAL 17280

// bf16 transposed image layout (u16 offsets)
#define IMG_EW2 0
#define IMG_MW1 4608
#define IMG_MW2 13312
#define IMG_TOTAL 17920

#define PREP_BLOCKS 138
#define HIST_BLOCKS 1024

// ---------------------------------------------------------------------------
// Fused kernel A: weight prep (self-detecting dtype) || target histogram.
// ---------------------------------------------------------------------------
__global__ __launch_bounds__(256) void prep_hist_k(Ptrs a, u16* img, float* fw,
                                                   const int* __restrict__ eidx,
                                                   int* __restrict__ cnt,
                                                   long E, int G) {
  const int t = threadIdx.x;
  if ((int)blockIdx.x >= PREP_BLOCKS) {
    long i = (long)(blockIdx.x - PREP_BLOCKS) * 256 + t;
    const long stride = (long)HIST_BLOCKS * 256;
    for (; i < E; i += stride) {
      int tg = eidx[E + i];
      if (tg >= 0 && tg < G) atomicAdd(&cnt[tg], 1);
    }
    return;
  }
  int i = blockIdx.x * 256 + t;
  if (i < IMG_TOTAL) {
    const void* bp; int n; long si; bool real;
    if (i < IMG_MW1) { int nn = i / 72, k = i % 72; bp = a.p[10]; n = 4096; real = k < 64; si = (long)k * 64 + nn; }
    else if (i < IMG_MW2) { int t2 = i - IMG_MW1; int nn = t2 / 136, k = t2 % 136; bp = a.p[12]; n = 8192; real = k < 128; si = (long)k * 64 + nn; }
    else { int t2 = i - IMG_MW2; int nn = t2 / 72, k = t2 % 72; bp = a.p[14]; n = 4096; real = k < 64; si = (long)k * 64 + nn; }
    u16 val = 0;
    if (real) { int isf = detect1(bp, n); val = f2b(loadF(bp, si, isf)); }
    img[i] = val;
  } else if (i < IMG_TOTAL + FW_TOTAL) {
    int j = i - IMG_TOTAL;
    const void* bp; int n; long si;
    if (j < 4096)       { bp = a.p[4];  n = 4096; si = j; }
    else if (j < 8192)  { bp = a.p[6];  n = 4096; si = j - 4096; }
    else if (j < 12288) { bp = a.p[16]; n = 4096; si = j - 8192; }
    else if (j < 16384) { bp = a.p[18]; n = 4096; si = j - 12288; }
    else if (j < 16768) { bp = a.p[8];  n = 384;  si = j - 16384; }
    else {
      int b = j - 16768; int seg = b >> 6; si = b & 63; n = 64;
      switch (seg) {
        case 0: bp = a.p[5];  break;
        case 1: bp = a.p[7];  break;
        case 2: bp = a.p[17]; break;
        case 3: bp = a.p[19]; break;
        case 4: bp = a.p[9];  break;
        case 5: bp = a.p[11]; break;
        case 6: bp = a.p[13]; break;
        default: bp = a.p[15]; break;
      }
    }
    int isf = detect1(bp, n);
    fw[j] = loadF(bp, si, isf);
  }
}

// ---------------------------------------------------------------------------
// Fused kernel B: node MLP (self-detecting dtype) || per-256-chunk scan.
// ---------------------------------------------------------------------------
__global__ __launch_bounds__(256) void node_scan_k(
    const void* x, const float* __restrict__ fw, u16* __restrict__ out, int nrows,
    const int* __restrict__ cnt, int* __restrict__ cursor, int* __restrict__ bsum,
    int G, int nodeBlocks)
{
  __shared__ float xs[64][68];
  __shared__ float w1s[64][68];
  __shared__ float w2s[64][68];
  __shared__ float b1s[64];
  __shared__ float b2s[64];
  __shared__ int sd2[256];
  __shared__ int xdet;
  const int t = threadIdx.x;

  if ((int)blockIdx.x >= nodeBlocks) {
    int b2 = blockIdx.x - nodeBlocks;
    int i = b2 * 256 + t;
    int v = (i < G) ? cnt[i] : 0;
    sd2[t] = v;
    __syncthreads();
    for (int off = 1; off < 256; off <<= 1) {
      int x2 = (t >= off) ? sd2[t - off] : 0;
      __syncthreads();
      sd2[t] += x2;
      __syncthreads();
    }
    if (i < G) cursor[i] = sd2[t] - v;
    if (t == 255) bsum[b2] = sd2[255];
    return;
  }
  if (t == 0) xdet = 0;
  __syncthreads();
  {
    const u16* q = (const u16*)x;
    int c = 0;
    for (int i = t; i < 4096; i += 256) c += (((q[i] >> 7) & 0xffu) >= 0xC0u) ? 1 : 0;
    if (c) atomicAdd(&xdet, c);
  }
  const long rbase = (long)blockIdx.x * 64;
  for (int i = t; i < 4096; i += 256) {
    int k = i >> 6, cc = i & 63;
    w1s[k][cc] = fw[FW_NW1 + i];
    w2s[k][cc] = fw[FW_NW2 + i];
  }
  if (t < 64) { b1s[t] = fw[FW_NB1 + t]; b2s[t] = fw[FW_NB2 + t]; }
  __syncthreads();
  const int xf = xdet >= 2;
  {
    int row = t >> 2, ch = t & 3;
    long rg = rbase + row;
    if (rg < nrows) {
      if (xf) {
        const float* xp = (const float*)x + rg * 64 + ch * 16;
#pragma unroll
        for (int m = 0; m < 16; ++m) xs[row][ch * 16 + m] = xp[m];
      } else {
        const u16* xp = (const u16*)x + rg * 64 + ch * 16;
#pragma unroll
        for (int m = 0; m < 16; ++m) xs[row][ch * 16 + m] = b2f(xp[m]);
      }
    } else {
#pragma unroll
      for (int m = 0; m < 16; ++m) xs[row][ch * 16 + m] = 0.f;
    }
  }
  __syncthreads();
  const int r0 = (t >> 4) * 4, c0 = (t & 15) * 4;
  float acc[4][4];
#pragma unroll
  for (int i = 0; i < 4; ++i)
#pragma unroll
    for (int j = 0; j < 4; ++j) acc[i][j] = b1s[c0 + j];
  for (int k = 0; k < 64; ++k) {
    float w0 = w1s[k][c0], w1v = w1s[k][c0 + 1], w2v = w1s[k][c0 + 2], w3v = w1s[k][c0 + 3];
#pragma unroll
    for (int i = 0; i < 4; ++i) {
      float av = xs[r0 + i][k];
      acc[i][0] = fmaf(av, w0, acc[i][0]);
      acc[i][1] = fmaf(av, w1v, acc[i][1]);
      acc[i][2] = fmaf(av, w2v, acc[i][2]);
      acc[i][3] = fmaf(av, w3v, acc[i][3]);
    }
  }
  __syncthreads();
#pragma unroll
  for (int i = 0; i < 4; ++i)
#pragma unroll
    for (int j = 0; j < 4; ++j) xs[r0 + i][c0 + j] = silu_f(acc[i][j]);
  __syncthreads();
  float acc2[4][4];
#pragma unroll
  for (int i = 0; i < 4; ++i)
#pragma unroll
    for (int j = 0; j < 4; ++j) acc2[i][j] = b2s[c0 + j];
  for (int k = 0; k < 64; ++k) {
    float w0 = w2s[k][c0], w1v = w2s[k][c0 + 1], w2v = w2s[k][c0 + 2], w3v = w2s[k][c0 + 3];
#pragma unroll
    for (int i = 0; i < 4; ++i) {
      float av = xs[r0 + i][k];
      acc2[i][0] = fmaf(av, w0, acc2[i][0]);
      acc2[i][1] = fmaf(av, w1v, acc2[i][1]);
      acc2[i][2] = fmaf(av, w2v, acc2[i][2]);
      acc2[i][3] = fmaf(av, w3v, acc2[i][3]);
    }
  }
#pragma unroll
  for (int i = 0; i < 4; ++i) {
    long rg = rbase + r0 + i;
    if (rg < nrows) {
#pragma unroll
      for (int j = 0; j < 4; ++j) out[rg * 64 + c0 + j] = f2b(acc2[i][j]);
    }
  }
}

// ---------------------------------------------------------------------------
// Kernel C: scatter into sorted order; inline top-level scan of bsum.
// pack: src (17 bits) | tgt<<17 (15 bits)
// ---------------------------------------------------------------------------
__global__ __launch_bounds__(256) void scat_k(const int* __restrict__ eidx,
                                              int* __restrict__ cursor,
                                              const int* __restrict__ bsum,
                                              unsigned int* __restrict__ pkS,
                                              int* __restrict__ evp,
                                              long E, int G, int NB2) {
  __shared__ int bo[256];
  const int t = threadIdx.x;
  int v = (t < NB2) ? bsum[t] : 0;
  bo[t] = v;
  __syncthreads();
  for (int off = 1; off < 256; off <<= 1) {
    int x2 = (t >= off) ? bo[t - off] : 0;
    __syncthreads();
    bo[t] += x2;
    __syncthreads();
  }
  if (blockIdx.x == 0 && t == 0) *evp = bo[NB2 - 1];
  int excl = bo[t] - v;
  __syncthreads();
  bo[t] = excl;
  __syncthreads();
  long i = (long)blockIdx.x * 256 + t;
  const long stride = (long)gridDim.x * 256;
  for (; i < E; i += stride) {
    int tg = eidx[E + i];
    if (tg >= 0 && tg < G) {
      int s = eidx[i];
      int p = atomicAdd(&cursor[tg], 1) + bo[tg >> 8];
      pkS[p] = (unsigned int)s | ((unsigned int)tg << 17);
    }
  }
}

// ---------------------------------------------------------------------------
// Kernel D: edge pipeline, BARRIER-FREE. Each wave owns private 16-edge
// groups (LDS partitioned per wave); no __syncthreads in the loop. Per-wave
// DS ops are in-order; wave_barrier() pins compiler ordering (msgf overlays
// hA). Reduce boundary targets peeked straight from global pkS.
// ---------------------------------------------------------------------------
#define WGROUPS 4   // 16-edge groups per wave -> 256 edges per block

__global__ __launch_bounds__(256, 5) void edge_kernel(
    const void* node_pos, const void* grid_pos, const void* orient,
    const unsigned int* __restrict__ pkS, const int* __restrict__ evp,
    const u16* __restrict__ h_node, const u16* __restrict__ img,
    const float* __restrict__ fw,
    float* __restrict__ sums, int G)
{
  __shared__ __align__(16) u16 hA[4][16][136];   // per-wave; overlaid by msgf
  __shared__ __align__(16) u16 ef1[4][16][72];   // per-wave hidden acts
  __shared__ float eaf[4][16][6];
  __shared__ float w1e[6][64];
  __shared__ float biasE[4][64];
  __shared__ int tgt_sh[4][16];
  __shared__ int det[3];

  const int t = threadIdx.x;
  if (t < 3) det[t] = 0;
  __syncthreads();
  {
    int grp = t >> 6;
    if (grp < 3) {
      const u16* qq = (const u16*)(grp == 0 ? node_pos : grp == 1 ? grid_pos : orient);
      int cth = 0, l = t & 63;
      for (int i = l; i < 2048; i += 64) cth += (((qq[i] >> 7) & 0xffu) >= 0xC0u) ? 1 : 0;
      if (cth) atomicAdd(&det[grp], cth);
    }
  }
  for (int i = t; i < 384; i += 256) w1e[i / 64][i % 64] = fw[FW_EW1 + i];
  { int seg = t >> 6, cc = t & 63; biasE[seg][cc] = fw[FW_EB1 + seg * 64 + cc]; }
  __syncthreads();   // last block-wide barrier
  const int pf = det[0] >= 2, gf = det[1] >= 2, of = det[2] >= 2;
  const int Ev = *evp;

  const int lane = t & 63, w = t >> 6;
  const int q = lane >> 4, c = lane & 15;
  u16 (* __restrict__ hAw)[136] = hA[w];
  u16 (* __restrict__ ef1w)[72] = ef1[w];
  float (* __restrict__ eafw)[6] = eaf[w];
  float (* __restrict__ msgf)[66] = (float (*)[66])&hA[w][0][0];  // 16*66*4=4224 <= 4352
  int* tgtw = tgt_sh[w];
  const u16* wE2 = img + IMG_EW2;
  const u16* wM1 = img + IMG_MW1;
  const u16* wM2 = img + IMG_MW2;
  const f32x4 z = {0.f, 0.f, 0.f, 0.f};

  for (int g = 0; g < WGROUPS; ++g) {
    long base = ((long)blockIdx.x * 4 + w) * (WGROUPS * 16) + (long)g * 16;
    if (base >= Ev) break;
    // gather: geometry (lanes 0..15) + h_node rows (all lanes)
    if (lane < 16) {
      long eg = base + lane;
      int s = 0, tg = -1;
      if (eg < Ev) { unsigned int pk = pkS[eg]; s = (int)(pk & 0x1FFFFu); tg = (int)(pk >> 17); }
      tgtw[lane] = tg;
      int tgc = (tg >= 0) ? tg : 0;
      float ps[3], rel[3], tr[3];
#pragma unroll
      for (int i = 0; i < 3; ++i) {
        ps[i] = loadF(node_pos, (long)s * 3 + i, pf);
        rel[i] = loadF(grid_pos, (long)tgc * 3 + i, gf) - ps[i];
      }
#pragma unroll
      for (int j = 0; j < 3; ++j) tr[j] = 0.f;
#pragma unroll
      for (int i = 0; i < 3; ++i)
#pragma unroll
        for (int j = 0; j < 3; ++j)
          tr[j] = fmaf(rel[i], loadF(orient, (long)s * 9 + i * 3 + j, of), tr[j]);
      eafw[lane][0] = ps[0]; eafw[lane][1] = ps[1]; eafw[lane][2] = ps[2];
      eafw[lane][3] = tr[0]; eafw[lane][4] = tr[1]; eafw[lane][5] = tr[2];
    }
    {
      long eg = base + (lane >> 2);
      int s = 0;
      if (eg < Ev) s = (int)(pkS[eg] & 0x1FFFFu);
      const u16* hp = h_node + (long)s * 64 + (lane & 3) * 16;
      short8 v0 = *(const short8*)hp;
      short8 v1 = *(const short8*)(hp + 8);
      *(short8*)&hAw[lane >> 2][(lane & 3) * 16] = v0;
      *(short8*)&hAw[lane >> 2][(lane & 3) * 16 + 8] = v1;
    }
    __builtin_amdgcn_wave_barrier();

    // S1: edge MLP layer1 (K=6) f32 VALU -> silu -> ef1 (bf16)
    {
      int e = lane >> 2, c0 = (lane & 3) * 16;
      float a0 = eafw[e][0], a1 = eafw[e][1], a2 = eafw[e][2];
      float a3 = eafw[e][3], a4 = eafw[e][4], a5 = eafw[e][5];
      __align__(16) u16 tmp[16];
#pragma unroll
      for (int j = 0; j < 16; ++j) {
        int cc = c0 + j;
        float acc = biasE[0][cc];
        acc = fmaf(a0, w1e[0][cc], acc);
        acc = fmaf(a1, w1e[1][cc], acc);
        acc = fmaf(a2, w1e[2][cc], acc);
        acc = fmaf(a3, w1e[3][cc], acc);
        acc = fmaf(a4, w1e[4][cc], acc);
        acc = fmaf(a5, w1e[5][cc], acc);
        tmp[j] = f2b(silu_f(acc));
      }
      *(short8*)&ef1w[e][c0] = *(const short8*)tmp;
      *(short8*)&ef1w[e][c0 + 8] = *(const short8*)(tmp + 8);
    }
    __builtin_amdgcn_wave_barrier();
    // S2: edge MLP layer2 (K=64) -> hA cols 64..127
    {
      short8 a0 = *(const short8*)&ef1w[c][q * 8];
      short8 a1 = *(const short8*)&ef1w[c][32 + q * 8];
#pragma unroll
      for (int nt = 0; nt < 4; ++nt) {
        short8 b0 = *(const short8*)&wE2[(nt * 16 + c) * 72 + q * 8];
        short8 b1v = *(const short8*)&wE2[(nt * 16 + c) * 72 + 32 + q * 8];
        f32x4 acc = __builtin_amdgcn_mfma_f32_16x16x32_bf16(a0, b0, z, 0, 0, 0);
        acc = __builtin_amdgcn_mfma_f32_16x16x32_bf16(a1, b1v, acc, 0, 0, 0);
#pragma unroll
        for (int r = 0; r < 4; ++r) {
          int row = q * 4 + r, col = nt * 16 + c;
          hAw[row][64 + col] = f2b(acc[r] + biasE[1][col]);
        }
      }
    }
    __builtin_amdgcn_wave_barrier();
    // S3: msg MLP layer1 (K=128) -> silu -> ef1
    {
      short8 a0 = *(const short8*)&hAw[c][q * 8];
      short8 a1 = *(const short8*)&hAw[c][32 + q * 8];
      short8 a2 = *(const short8*)&hAw[c][64 + q * 8];
      short8 a3 = *(const short8*)&hAw[c][96 + q * 8];
#pragma unroll
      for (int nt = 0; nt < 4; ++nt) {
        const u16* wp = &wM1[(nt * 16 + c) * 136];
        f32x4 acc = __builtin_amdgcn_mfma_f32_16x16x32_bf16(a0, *(const short8*)(wp + q * 8), z, 0, 0, 0);
        acc = __builtin_amdgcn_mfma_f32_16x16x32_bf16(a1, *(const short8*)(wp + 32 + q * 8), acc, 0, 0, 0);
        acc = __builtin_amdgcn_mfma_f32_16x16x32_bf16(a2, *(const short8*)(wp + 64 + q * 8), acc, 0, 0, 0);
        acc = __builtin_amdgcn_mfma_f32_16x16x32_bf16(a3, *(const short8*)(wp + 96 + q * 8), acc, 0, 0, 0);
#pragma unroll
        for (int r = 0; r < 4; ++r) {
          int row = q * 4 + r, col = nt * 16 + c;
          ef1w[row][col] = f2b(silu_f(acc[r] + biasE[2][col]));
        }
      }
    }
    __builtin_amdgcn_wave_barrier();   // hA (as u16) dead; msgf overlays it
    // S4: msg MLP layer2 (K=64) -> msgf (f32, +bias)
    {
      short8 a0 = *(const short8*)&ef1w[c][q * 8];
      short8 a1 = *(const short8*)&ef1w[c][32 + q * 8];
#pragma unroll
      for (int nt = 0; nt < 4; ++nt) {
        short8 b0 = *(const short8*)&wM2[(nt * 16 + c) * 72 + q * 8];
        short8 b1v = *(const short8*)&wM2[(nt * 16 + c) * 72 + 32 + q * 8];
        f32x4 acc = __builtin_amdgcn_mfma_f32_16x16x32_bf16(a0, b0, z, 0, 0, 0);
        acc = __builtin_amdgcn_mfma_f32_16x16x32_bf16(a1, b1v, acc, 0, 0, 0);
#pragma unroll
        for (int r = 0; r < 4; ++r) {
          int row = q * 4 + r, col = nt * 16 + c;
          msgf[row][col] = acc[r] + biasE[3][col];
        }
      }
    }
    __builtin_amdgcn_wave_barrier();
    // Run-reduction over the wave's 16 rows; col = lane. Boundary targets
    // peeked from global pkS (same addr per wave -> broadcast load).
    {
      int lt = (base > 0) ? (int)(pkS[base - 1] >> 17) : -2;
      int rt = (base + 16 < Ev) ? (int)(pkS[base + 16] >> 17) : -2;
      int cur = tgtw[0];
      float run = msgf[0][lane];
      bool lopen = (lt == cur);
#pragma unroll
      for (int r2 = 1; r2 < 16; ++r2) {
        int tg = tgtw[r2];
        float v = msgf[r2][lane];
        if (tg == cur) {
          run += v;
        } else {
          if (cur >= 0) {
            if (lopen) unsafeAtomicAdd(&sums[(long)cur * 64 + lane], run);
            else sums[(long)cur * 64 + lane] = run;
          }
          cur = tg; run = v; lopen = false;
        }
      }
      bool ropen = (rt == cur);
      if (cur >= 0) {
        if (lopen || ropen) unsafeAtomicAdd(&sums[(long)cur * 64 + lane], run);
        else sums[(long)cur * 64 + lane] = run;
      }
    }
    __builtin_amdgcn_wave_barrier();   // msgf consumed before next gather
  }
}

// ---------------------------------------------------------------------------
// Kernel E: scatter-mean + update MLP (f32) -> f32 out [G,64]
// ---------------------------------------------------------------------------
__global__ __launch_bounds__(256) void upd_mlp(
    const float* __restrict__ sums, const int* __restrict__ cnt,
    const float* __restrict__ fw, float* __restrict__ out, int nrows)
{
  __shared__ float xs[64][68];
  __shared__ float w1s[64][68];
  __shared__ float w2s[64][68];
  __shared__ float b1s[64];
  __shared__ float b2s[64];
  const int t = threadIdx.x;
  const long rbase = (long)blockIdx.x * 64;
  for (int i = t; i < 4096; i += 256) {
    int k = i >> 6, cc = i & 63;
    w1s[k][cc] = fw[FW_UW1 + i];
    w2s[k][cc] = fw[FW_UW2 + i];
  }
  if (t < 64) { b1s[t] = fw[FW_UB1 + t]; b2s[t] = fw[FW_UB2 + t]; }
  {
    int row = t >> 2, ch = t & 3;
    long rg = rbase + row;
    if (rg < nrows) {
      float inv = 1.0f / fmaxf((float)cnt[rg], 1.0f);
      const float* p = sums + rg * 64 + ch * 16;
#pragma unroll
      for (int m = 0; m < 16; ++m) xs[row][ch * 16 + m] = p[m] * inv;
    } else {
#pragma unroll
      for (int m = 0; m < 16; ++m) xs[row][ch * 16 + m] = 0.f;
    }
  }
  __syncthreads();
  const int r0 = (t >> 4) * 4, c0 = (t & 15) * 4;
  float acc[4][4];
#pragma unroll
  for (int i = 0; i < 4; ++i)
#pragma unroll
    for (int j = 0; j < 4; ++j) acc[i][j] = b1s[c0 + j];
  for (int k = 0; k < 64; ++k) {
    float w0 = w1s[k][c0], w1v = w1s[k][c0 + 1], w2v = w1s[k][c0 + 2], w3v = w1s[k][c0 + 3];
#pragma unroll
    for (int i = 0; i < 4; ++i) {
      float av = xs[r0 + i][k];
      acc[i][0] = fmaf(av, w0, acc[i][0]);
      acc[i][1] = fmaf(av, w1v, acc[i][1]);
      acc[i][2] = fmaf(av, w2v, acc[i][2]);
      acc[i][3] = fmaf(av, w3v, acc[i][3]);
    }
  }
  __syncthreads();
#pragma unroll
  for (int i = 0; i < 4; ++i)
#pragma unroll
    for (int j = 0; j < 4; ++j) xs[r0 + i][c0 + j] = silu_f(acc[i][j]);
  __syncthreads();
  float acc2[4][4];
#pragma unroll
  for (int i = 0; i < 4; ++i)
#pragma unroll
    for (int j = 0; j < 4; ++j) acc2[i][j] = b2s[c0 + j];
  for (int k = 0; k < 64; ++k) {
    float w0 = w2s[k][c0], w1v = w2s[k][c0 + 1], w2v = w2s[k][c0 + 2], w3v = w2s[k][c0 + 3];
#pragma unroll
    for (int i = 0; i < 4; ++i) {
      float av = xs[r0 + i][k];
      acc2[i][0] = fmaf(av, w0, acc2[i][0]);
      acc2[i][1] = fmaf(av, w1v, acc2[i][1]);
      acc2[i][2] = fmaf(av, w2v, acc2[i][2]);
      acc2[i][3] = fmaf(av, w3v, acc2[i][3]);
    }
  }
#pragma unroll
  for (int i = 0; i < 4; ++i) {
    long rg = rbase + r0 + i;
    if (rg < nrows) {
#pragma unroll
      for (int j = 0; j < 4; ++j) out[rg * 64 + c0 + j] = acc2[i][j];
    }
  }
}

// ---------------------------------------------------------------------------
extern "C" void kernel_launch(void* const* d_in, const int* in_sizes, int n_in,
                              void* d_out, int out_size, void* d_ws, size_t ws_size,
                              hipStream_t stream) {
  const int N = in_sizes[1] / 3;
  const int G = in_sizes[2] / 3;
  const long E = (long)in_sizes[4] / 2;
  const int NB2 = (G + 255) / 256;
  const int nodeBlocks = (N + 63) / 64;

  char* ws = (char*)d_ws;
  float* sums = (float*)ws;
  size_t off = (size_t)G * 256;
  int* cnt = (int*)(ws + off);     off += (size_t)G * 4;
  int* cursor = (int*)(ws + off);  off += (size_t)G * 4;
  int* bsum = (int*)(ws + off);    off += 1024;
  int* evp = (int*)(ws + off);     off += 256;
  unsigned int* pkS = (unsigned int*)(ws + off); off += (size_t)E * 4;
  u16* h_node = (u16*)(ws + off);  off += (size_t)N * 128;
  u16* img = (u16*)(ws + off);     off += (size_t)IMG_TOTAL * 2;
  float* fw = (float*)(ws + off);

  hipMemsetAsync(ws, 0, (size_t)G * 260, stream);

  Ptrs a;
  const int map[20] = {0,1,2,3, 5,6,7,8, 9,10,11,12, 13,14,15,16, 17,18,19,20};
  for (int i = 0; i < 20; ++i) a.p[i] = d_in[map[i]];

  prep_hist_k<<<PREP_BLOCKS + HIST_BLOCKS, 256, 0, stream>>>(
      a, img, fw, (const int*)d_in[4], cnt, E, G);
  node_scan_k<<<nodeBlocks + NB2, 256, 0, stream>>>(
      d_in[0], fw, h_node, N, cnt, cursor, bsum, G, nodeBlocks);
  scat_k<<<1024, 256, 0, stream>>>((const int*)d_in[4], cursor, bsum, pkS, evp, E, G, NB2);
  edge_kernel<<<(int)((E + 255) / 256), 256, 0, stream>>>(
      d_in[1], d_in[2], d_in[3], pkS, evp, h_node, img, fw, sums, G);
  upd_mlp<<<(G + 63) / 64, 256, 0, stream>>>(sums, cnt, fw, (float*)d_out, G);
}

// Round 8
// 487.980 us; speedup vs baseline: 1.1180x; 1.0131x over previous
//
#include <hip/hip_runtime.h>
#include <hip/hip_bf16.h>
#include <cstdint>

typedef __attribute__((ext_vector_type(8))) short short8;
typedef __attribute__((ext_vector_type(4))) float f32x4;
typedef unsigned short u16;

__device__ __forceinline__ float b2f(u16 u) {
  union { unsigned int i; float f; } v; v.i = ((unsigned int)u) << 16; return v.f;
}
// hardware RNE f32->bf16
__device__ __forceinline__ u16 f2b(float f) {
  __hip_bfloat16 h = __float2bfloat16(f);
  union { __hip_bfloat16 h; u16 u; } v; v.h = h; return v.u;
}
__device__ __forceinline__ float silu_f(float x) { return x / (1.0f + __expf(-x)); }

__device__ __forceinline__ float loadF(const void* p, long i, int isf32) {
  if (isf32) return ((const float*)p)[i];
  return b2f(((const u16*)p)[i]);
}

// dtype sniff bit: f32 data viewed as u16 -> low halves have uniform-random
// "bf16 exponent field": ~50% land outside [2^-63, 2^65). Genuine bf16
// N(0,1)/uniform data: none (zeros excluded).
__device__ __forceinline__ int sniffbit(u16 u) {
  unsigned e = (u >> 7) & 0xffu;
  return (e >= 0xC0u || (e < 0x40u && (u & 0x7fffu) != 0)) ? 1 : 0;
}
// per-thread sniff over up to 512 u16s (n = element count, >= u16 count avail)
__device__ __forceinline__ int detect1(const void* p, int n) {
  const u16* q = (const u16*)p;
  int m = n < 512 ? n : 512;
  int h = 0;
  for (int k = 0; k < m; ++k) h += sniffbit(q[k]);
  return h >= 2;
}

struct Ptrs { const void* p[20]; };

// f32 prepped-weight layout (float offsets)
#define FW_EW1 0
#define FW_UW1 384
#define FW_UW2 4480
#define FW_UB1 8576
#define FW_UB2 8640
#define FW_EB1 8704
#define FW_EB2 8768
#define FW_MB1 8832
#define FW_MB2 8896
#define FW_TOTAL 8960

// bf16 transposed image layout (u16 offsets)
#define IMG_EW2 0
#define IMG_MW1 4608
#define IMG_MW2 13312
#define IMG_TOTAL 17920

#define PREP_BLOCKS 105   // ceil((IMG_TOTAL + FW_TOTAL)/256)
#define HIST_BLOCKS 1024

// ---------------------------------------------------------------------------
// Kernel 1: node MLP | weight prep | histogram (all independent, one launch).
// Block roles: [0,nodeBlocks) node; [+PREP_BLOCKS) prep; rest hist.
// ---------------------------------------------------------------------------
__global__ __launch_bounds__(256) void fused_a(
    Ptrs a, u16* __restrict__ img, float* __restrict__ fw,
    const int* __restrict__ eidx, int* __restrict__ cnt,
    const void* x, u16* __restrict__ hout, int nrows,
    long E, int G, int nodeBlocks)
{
  const int t = threadIdx.x;
  const int b = blockIdx.x;

  if (b >= nodeBlocks + PREP_BLOCKS) {
    // ---- histogram ----
    long i = (long)(b - nodeBlocks - PREP_BLOCKS) * 256 + t;
    const long stride = (long)HIST_BLOCKS * 256;
    for (; i < E; i += stride) {
      int tg = eidx[E + i];
      if (tg >= 0 && tg < G) atomicAdd(&cnt[tg], 1);
    }
    return;
  }

  if (b >= nodeBlocks) {
    // ---- weight prep (transposed bf16 image + f32 ew1/upd/biases) ----
    int i = (b - nodeBlocks) * 256 + t;
    if (i < IMG_TOTAL) {
      const void* bp; int n; long si; bool real;
      if (i < IMG_MW1) { int nn = i / 72, k = i % 72; bp = a.p[10]; n = 4096; real = k < 64; si = (long)k * 64 + nn; }
      else if (i < IMG_MW2) { int t2 = i - IMG_MW1; int nn = t2 / 136, k = t2 % 136; bp = a.p[12]; n = 8192; real = k < 128; si = (long)k * 64 + nn; }
      else { int t2 = i - IMG_MW2; int nn = t2 / 72, k = t2 % 72; bp = a.p[14]; n = 4096; real = k < 64; si = (long)k * 64 + nn; }
      u16 val = 0;
      if (real) { int isf = detect1(bp, n); val = f2b(loadF(bp, si, isf)); }
      img[i] = val;
    } else if (i < IMG_TOTAL + FW_TOTAL) {
      int j = i - IMG_TOTAL;
      const void* bp; int n; long si;
      if (j < 384)        { bp = a.p[8];  n = 384;  si = j; }             // ew1
      else if (j < 4480)  { bp = a.p[16]; n = 4096; si = j - 384; }       // uw1
      else if (j < 8576)  { bp = a.p[18]; n = 4096; si = j - 4480; }      // uw2
      else {
        int bb = j - 8576; int seg = bb >> 6; si = bb & 63; n = 64;
        switch (seg) {
          case 0: bp = a.p[17]; break;  // ub1
          case 1: bp = a.p[19]; break;  // ub2
          case 2: bp = a.p[9];  break;  // eb1
          case 3: bp = a.p[11]; break;  // eb2
          case 4: bp = a.p[13]; break;  // mb1
          default: bp = a.p[15]; break; // mb2
        }
      }
      int isf = detect1(bp, n);
      fw[j] = loadF(bp, si, isf);
    }
    return;
  }

  // ---- node MLP (raw weights, self-detect) ----
  __shared__ float xs[64][68];
  __shared__ float w1s[64][68];
  __shared__ float w2s[64][68];
  __shared__ float b1s[64];
  __shared__ float b2s[64];
  __shared__ int nd[5];
  if (t < 5) nd[t] = 0;
  __syncthreads();
  {
    int c = 0;
    const u16* q0 = (const u16*)x;
    for (int i = t; i < 2048; i += 256) c += sniffbit(q0[i]);
    if (c) atomicAdd(&nd[0], c);
    c = 0;
    const u16* q1 = (const u16*)a.p[4];
    for (int i = t; i < 2048; i += 256) c += sniffbit(q1[i]);
    if (c) atomicAdd(&nd[1], c);
    c = 0;
    const u16* q2 = (const u16*)a.p[6];
    for (int i = t; i < 2048; i += 256) c += sniffbit(q2[i]);
    if (c) atomicAdd(&nd[2], c);
    if (t < 64) {
      if (sniffbit(((const u16*)a.p[5])[t])) atomicAdd(&nd[3], 1);
      if (sniffbit(((const u16*)a.p[7])[t])) atomicAdd(&nd[4], 1);
    }
  }
  __syncthreads();
  const int xf = nd[0] >= 2, f1 = nd[1] >= 2, f2 = nd[2] >= 2;
  const int fb1 = nd[3] >= 2, fb2 = nd[4] >= 2;
  const long rbase = (long)b * 64;
  for (int i = t; i < 4096; i += 256) {
    int k = i >> 6, cc = i & 63;
    w1s[k][cc] = loadF(a.p[4], i, f1);
    w2s[k][cc] = loadF(a.p[6], i, f2);
  }
  if (t < 64) { b1s[t] = loadF(a.p[5], t, fb1); b2s[t] = loadF(a.p[7], t, fb2); }
  {
    int row = t >> 2, ch = t & 3;
    long rg = rbase + row;
    if (rg < nrows) {
      if (xf) {
        const float* xp = (const float*)x + rg * 64 + ch * 16;
#pragma unroll
        for (int m = 0; m < 16; ++m) xs[row][ch * 16 + m] = xp[m];
      } else {
        const u16* xp = (const u16*)x + rg * 64 + ch * 16;
#pragma unroll
        for (int m = 0; m < 16; ++m) xs[row][ch * 16 + m] = b2f(xp[m]);
      }
    } else {
#pragma unroll
      for (int m = 0; m < 16; ++m) xs[row][ch * 16 + m] = 0.f;
    }
  }
  __syncthreads();
  const int r0 = (t >> 4) * 4, c0 = (t & 15) * 4;
  float acc[4][4];
#pragma unroll
  for (int i = 0; i < 4; ++i)
#pragma unroll
    for (int j = 0; j < 4; ++j) acc[i][j] = b1s[c0 + j];
  for (int k = 0; k < 64; ++k) {
    float w0 = w1s[k][c0], w1v = w1s[k][c0 + 1], w2v = w1s[k][c0 + 2], w3v = w1s[k][c0 + 3];
#pragma unroll
    for (int i = 0; i < 4; ++i) {
      float av = xs[r0 + i][k];
      acc[i][0] = fmaf(av, w0, acc[i][0]);
      acc[i][1] = fmaf(av, w1v, acc[i][1]);
      acc[i][2] = fmaf(av, w2v, acc[i][2]);
      acc[i][3] = fmaf(av, w3v, acc[i][3]);
    }
  }
  __syncthreads();
#pragma unroll
  for (int i = 0; i < 4; ++i)
#pragma unroll
    for (int j = 0; j < 4; ++j) xs[r0 + i][c0 + j] = silu_f(acc[i][j]);
  __syncthreads();
  float acc2[4][4];
#pragma unroll
  for (int i = 0; i < 4; ++i)
#pragma unroll
    for (int j = 0; j < 4; ++j) acc2[i][j] = b2s[c0 + j];
  for (int k = 0; k < 64; ++k) {
    float w0 = w2s[k][c0], w1v = w2s[k][c0 + 1], w2v = w2s[k][c0 + 2], w3v = w2s[k][c0 + 3];
#pragma unroll
    for (int i = 0; i < 4; ++i) {
      float av = xs[r0 + i][k];
      acc2[i][0] = fmaf(av, w0, acc2[i][0]);
      acc2[i][1] = fmaf(av, w1v, acc2[i][1]);
      acc2[i][2] = fmaf(av, w2v, acc2[i][2]);
      acc2[i][3] = fmaf(av, w3v, acc2[i][3]);
    }
  }
#pragma unroll
  for (int i = 0; i < 4; ++i) {
    long rg = rbase + r0 + i;
    if (rg < nrows) {
#pragma unroll
      for (int j = 0; j < 4; ++j) hout[rg * 64 + c0 + j] = f2b(acc2[i][j]);
    }
  }
}

// ---------------------------------------------------------------------------
// Kernel 2: per-256-chunk exclusive scan of cnt -> cursor, chunk sums -> bsum.
// ---------------------------------------------------------------------------
__global__ __launch_bounds__(256) void scan_k(const int* __restrict__ cnt,
                                              int* __restrict__ cursor,
                                              int* __restrict__ bsum, int G) {
  __shared__ int sd[256];
  const int t = threadIdx.x;
  int i = blockIdx.x * 256 + t;
  int v = (i < G) ? cnt[i] : 0;
  sd[t] = v;
  __syncthreads();
  for (int off = 1; off < 256; off <<= 1) {
    int x2 = (t >= off) ? sd[t - off] : 0;
    __syncthreads();
    sd[t] += x2;
    __syncthreads();
  }
  if (i < G) cursor[i] = sd[t] - v;
  if (t == 255) bsum[blockIdx.x] = sd[255];
}

// ---------------------------------------------------------------------------
// Kernel 3: scatter into sorted order; inline top-level scan of bsum (<=256).
// pack: src (17 bits) | tgt<<17 (15 bits)
// ---------------------------------------------------------------------------
__global__ __launch_bounds__(256) void scat_k(const int* __restrict__ eidx,
                                              int* __restrict__ cursor,
                                              const int* __restrict__ bsum,
                                              unsigned int* __restrict__ pkS,
                                              int* __restrict__ evp,
                                              long E, int G, int NB2) {
  __shared__ int bo[256];
  const int t = threadIdx.x;
  int v = (t < NB2) ? bsum[t] : 0;
  bo[t] = v;
  __syncthreads();
  for (int off = 1; off < 256; off <<= 1) {
    int x2 = (t >= off) ? bo[t - off] : 0;
    __syncthreads();
    bo[t] += x2;
    __syncthreads();
  }
  if (blockIdx.x == 0 && t == 0) *evp = bo[NB2 - 1];
  int excl = bo[t] - v;
  __syncthreads();
  bo[t] = excl;
  __syncthreads();
  long i = (long)blockIdx.x * 256 + t;
  const long stride = (long)gridDim.x * 256;
  for (; i < E; i += stride) {
    int tg = eidx[E + i];
    if (tg >= 0 && tg < G) {
      int s = eidx[i];
      int p = atomicAdd(&cursor[tg], 1) + bo[tg >> 8];
      pkS[p] = (unsigned int)s | ((unsigned int)tg << 17);
    }
  }
}

// ---------------------------------------------------------------------------
// Kernel 4: edge pipeline (R5 block-tile structure — best measured) over
// SORTED edges. msgf overlays hA after S3 (~31 KB LDS, 5 blocks/CU).
// ---------------------------------------------------------------------------
#define ETILES 4

__global__ __launch_bounds__(256, 5) void edge_kernel(
    const void* node_pos, const void* grid_pos, const void* orient,
    const unsigned int* __restrict__ pkS, const int* __restrict__ evp,
    const u16* __restrict__ h_node, const u16* __restrict__ img,
    const float* __restrict__ fw,
    float* __restrict__ sums, int G)
{
  __shared__ __align__(16) u16 hA[64][136];    // msg_in; after S3 reused as msgf
  __shared__ __align__(16) u16 ef1[64][72];
  __shared__ float eaf[64][6];
  __shared__ float w1e[6][64];
  __shared__ float biasE[4][64];
  __shared__ int src_s[64];
  __shared__ int tgt_s[64];
  __shared__ int det[3];
  float (*msgf)[66] = (float (*)[66])&hA[0][0];   // 64*66*4 = 16896 <= 17408

  const int t = threadIdx.x;
  if (t < 3) det[t] = 0;
  __syncthreads();
  {
    int grp = t >> 6;
    if (grp < 3) {
      const u16* qq = (const u16*)(grp == 0 ? node_pos : grp == 1 ? grid_pos : orient);
      int cth = 0, l = t & 63;
      for (int i = l; i < 2048; i += 64) cth += sniffbit(qq[i]);
      if (cth) atomicAdd(&det[grp], cth);
    }
  }
  for (int i = t; i < 384; i += 256) w1e[i / 64][i % 64] = fw[FW_EW1 + i];
  { int seg = t >> 6, cc = t & 63; biasE[seg][cc] = fw[FW_EB1 + seg * 64 + cc]; }
  __syncthreads();
  const int pf = det[0] >= 2, gf = det[1] >= 2, of = det[2] >= 2;
  const int Ev = *evp;

  const int lane = t & 63, w = t >> 6;
  const int q = lane >> 4, c = lane & 15;
  const int m0 = w * 16;
  const u16* wE2 = img + IMG_EW2;
  const u16* wM1 = img + IMG_MW1;
  const u16* wM2 = img + IMG_MW2;
  const f32x4 z = {0.f, 0.f, 0.f, 0.f};

  for (int tile = 0; tile < ETILES; ++tile) {
    long base = ((long)blockIdx.x * ETILES + tile) * 64;
    if (base >= Ev) break;
    __syncthreads();  // previous tile's reduce still reads msgf/tgt_s
    if (t < 64) {
      long eg = base + t;
      int s, tg;
      if (eg < Ev) {
        unsigned int pk = pkS[eg];
        s = (int)(pk & 0x1FFFFu);
        tg = (int)(pk >> 17);
      } else { s = 0; tg = -1; }
      src_s[t] = s;
      tgt_s[t] = tg;
      int tgc = (tg >= 0) ? tg : 0;
      float ps[3], rel[3], tr[3];
#pragma unroll
      for (int i = 0; i < 3; ++i) {
        ps[i] = loadF(node_pos, (long)s * 3 + i, pf);
        rel[i] = loadF(grid_pos, (long)tgc * 3 + i, gf) - ps[i];
      }
#pragma unroll
      for (int j = 0; j < 3; ++j) tr[j] = 0.f;
#pragma unroll
      for (int i = 0; i < 3; ++i)
#pragma unroll
        for (int j = 0; j < 3; ++j)
          tr[j] = fmaf(rel[i], loadF(orient, (long)s * 9 + i * 3 + j, of), tr[j]);
      eaf[t][0] = ps[0]; eaf[t][1] = ps[1]; eaf[t][2] = ps[2];
      eaf[t][3] = tr[0]; eaf[t][4] = tr[1]; eaf[t][5] = tr[2];
    }
    __syncthreads();  // src_s ready (and msgf fully consumed)
    {
      int e = t >> 2, ch = t & 3;
      const u16* hp = h_node + (long)src_s[e] * 64 + ch * 16;
      short8 v0 = *(const short8*)hp;
      short8 v1 = *(const short8*)(hp + 8);
      *(short8*)&hA[e][ch * 16] = v0;
      *(short8*)&hA[e][ch * 16 + 8] = v1;
    }
    __syncthreads();  // eaf + hA(h_node half) ready

    // S1: edge MLP layer1 (K=6) f32 VALU -> silu -> ef1 (bf16)
    {
      int e = t >> 2, c0 = (t & 3) * 16;
      float a0 = eaf[e][0], a1 = eaf[e][1], a2 = eaf[e][2];
      float a3 = eaf[e][3], a4 = eaf[e][4], a5 = eaf[e][5];
      __align__(16) u16 tmp[16];
#pragma unroll
      for (int j = 0; j < 16; ++j) {
        int cc = c0 + j;
        float acc = biasE[0][cc];
        acc = fmaf(a0, w1e[0][cc], acc);
        acc = fmaf(a1, w1e[1][cc], acc);
        acc = fmaf(a2, w1e[2][cc], acc);
        acc = fmaf(a3, w1e[3][cc], acc);
        acc = fmaf(a4, w1e[4][cc], acc);
        acc = fmaf(a5, w1e[5][cc], acc);
        tmp[j] = f2b(silu_f(acc));
      }
      *(short8*)&ef1[e][c0] = *(const short8*)tmp;
      *(short8*)&ef1[e][c0 + 8] = *(const short8*)(tmp + 8);
    }
    __syncthreads();
    // S2: edge MLP layer2 (K=64) -> hA cols 64..127
    {
      short8 a0 = *(const short8*)&ef1[m0 + c][q * 8];
      short8 a1 = *(const short8*)&ef1[m0 + c][32 + q * 8];
#pragma unroll
      for (int nt = 0; nt < 4; ++nt) {
        short8 b0 = *(const short8*)&wE2[(nt * 16 + c) * 72 + q * 8];
        short8 b1v = *(const short8*)&wE2[(nt * 16 + c) * 72 + 32 + q * 8];
        f32x4 acc = __builtin_amdgcn_mfma_f32_16x16x32_bf16(a0, b0, z, 0, 0, 0);
        acc = __builtin_amdgcn_mfma_f32_16x16x32_bf16(a1, b1v, acc, 0, 0, 0);
#pragma unroll
        for (int r = 0; r < 4; ++r) {
          int row = m0 + q * 4 + r, col = nt * 16 + c;
          hA[row][64 + col] = f2b(acc[r] + biasE[1][col]);
        }
      }
    }
    __syncthreads();
    // S3: msg MLP layer1 (K=128) -> silu -> ef1
    {
      short8 a0 = *(const short8*)&hA[m0 + c][q * 8];
      short8 a1 = *(const short8*)&hA[m0 + c][32 + q * 8];
      short8 a2 = *(const short8*)&hA[m0 + c][64 + q * 8];
      short8 a3 = *(const short8*)&hA[m0 + c][96 + q * 8];
#pragma unroll
      for (int nt = 0; nt < 4; ++nt) {
        const u16* wp = &wM1[(nt * 16 + c) * 136];
        f32x4 acc = __builtin_amdgcn_mfma_f32_16x16x32_bf16(a0, *(const short8*)(wp + q * 8), z, 0, 0, 0);
        acc = __builtin_amdgcn_mfma_f32_16x16x32_bf16(a1, *(const short8*)(wp + 32 + q * 8), acc, 0, 0, 0);
        acc = __builtin_amdgcn_mfma_f32_16x16x32_bf16(a2, *(const short8*)(wp + 64 + q * 8), acc, 0, 0, 0);
        acc = __builtin_amdgcn_mfma_f32_16x16x32_bf16(a3, *(const short8*)(wp + 96 + q * 8), acc, 0, 0, 0);
#pragma unroll
        for (int r = 0; r < 4; ++r) {
          int row = m0 + q * 4 + r, col = nt * 16 + c;
          ef1[row][col] = f2b(silu_f(acc[r] + biasE[2][col]));
        }
      }
    }
    __syncthreads();  // hA dead from here: msgf overlays it
    // S4: msg MLP layer2 (K=64) -> msgf (f32, +bias)
    {
      short8 a0 = *(const short8*)&ef1[m0 + c][q * 8];
      short8 a1 = *(const short8*)&ef1[m0 + c][32 + q * 8];
#pragma unroll
      for (int nt = 0; nt < 4; ++nt) {
        short8 b0 = *(const short8*)&wM2[(nt * 16 + c) * 72 + q * 8];
        short8 b1v = *(const short8*)&wM2[(nt * 16 + c) * 72 + 32 + q * 8];
        f32x4 acc = __builtin_amdgcn_mfma_f32_16x16x32_bf16(a0, b0, z, 0, 0, 0);
        acc = __builtin_amdgcn_mfma_f32_16x16x32_bf16(a1, b1v, acc, 0, 0, 0);
#pragma unroll
        for (int r = 0; r < 4; ++r) {
          int row = m0 + q * 4 + r, col = nt * 16 + c;
          msgf[row][col] = acc[r] + biasE[3][col];
        }
      }
    }
    __syncthreads();
    // Run-reduction: wave w walks rows [16w,16w+16), col = lane.
    // Interior runs plain-store (sole writer), boundary runs atomicAdd.
    {
      int col = lane;
      int r0 = w * 16;
      int cur = tgt_s[r0];
      float run = msgf[r0][col];
      bool lopen = (r0 == 0) ? true : (tgt_s[r0 - 1] == cur);
#pragma unroll
      for (int r2 = 1; r2 < 16; ++r2) {
        int r = r0 + r2;
        int tg = tgt_s[r];
        float v = msgf[r][col];
        if (tg == cur) {
          run += v;
        } else {
          if (cur >= 0) {
            if (lopen) unsafeAtomicAdd(&sums[(long)cur * 64 + col], run);
            else sums[(long)cur * 64 + col] = run;
          }
          cur = tg; run = v; lopen = false;
        }
      }
      bool ropen = (r0 + 16 >= 64) ? true : (tgt_s[r0 + 16] == cur);
      if (cur >= 0) {
        if (lopen || ropen) unsafeAtomicAdd(&sums[(long)cur * 64 + col], run);
        else sums[(long)cur * 64 + col] = run;
      }
    }
  }
}

// ---------------------------------------------------------------------------
// Kernel 5: scatter-mean + update MLP (f32) -> f32 out [G,64]
// ---------------------------------------------------------------------------
__global__ __launch_bounds__(256) void upd_mlp(
    const float* __restrict__ sums, const int* __restrict__ cnt,
    const float* __restrict__ fw, float* __restrict__ out, int nrows)
{
  __shared__ float xs[64][68];
  __shared__ float w1s[64][68];
  __shared__ float w2s[64][68];
  __shared__ float b1s[64];
  __shared__ float b2s[64];
  const int t = threadIdx.x;
  const long rbase = (long)blockIdx.x * 64;
  for (int i = t; i < 4096; i += 256) {
    int k = i >> 6, cc = i & 63;
    w1s[k][cc] = fw[FW_UW1 + i];
    w2s[k][cc] = fw[FW_UW2 + i];
  }
  if (t < 64) { b1s[t] = fw[FW_UB1 + t]; b2s[t] = fw[FW_UB2 + t]; }
  {
    int row = t >> 2, ch = t & 3;
    long rg = rbase + row;
    if (rg < nrows) {
      float inv = 1.0f / fmaxf((float)cnt[rg], 1.0f);
      const float* p = sums + rg * 64 + ch * 16;
#pragma unroll
      for (int m = 0; m < 16; ++m) xs[row][ch * 16 + m] = p[m] * inv;
    } else {
#pragma unroll
      for (int m = 0; m < 16; ++m) xs[row][ch * 16 + m] = 0.f;
    }
  }
  __syncthreads();
  const int r0 = (t >> 4) * 4, c0 = (t & 15) * 4;
  float acc[4][4];
#pragma unroll
  for (int i = 0; i < 4; ++i)
#pragma unroll
    for (int j = 0; j < 4; ++j) acc[i][j] = b1s[c0 + j];
  for (int k = 0; k < 64; ++k) {
    float w0 = w1s[k][c0], w1v = w1s[k][c0 + 1], w2v = w1s[k][c0 + 2], w3v = w1s[k][c0 + 3];
#pragma unroll
    for (int i = 0; i < 4; ++i) {
      float av = xs[r0 + i][k];
      acc[i][0] = fmaf(av, w0, acc[i][0]);
      acc[i][1] = fmaf(av, w1v, acc[i][1]);
      acc[i][2] = fmaf(av, w2v, acc[i][2]);
      acc[i][3] = fmaf(av, w3v, acc[i][3]);
    }
  }
  __syncthreads();
#pragma unroll
  for (int i = 0; i < 4; ++i)
#pragma unroll
    for (int j = 0; j < 4; ++j) xs[r0 + i][c0 + j] = silu_f(acc[i][j]);
  __syncthreads();
  float acc2[4][4];
#pragma unroll
  for (int i = 0; i < 4; ++i)
#pragma unroll
    for (int j = 0; j < 4; ++j) acc2[i][j] = b2s[c0 + j];
  for (int k = 0; k < 64; ++k) {
    float w0 = w2s[k][c0], w1v = w2s[k][c0 + 1], w2v = w2s[k][c0 + 2], w3v = w2s[k][c0 + 3];
#pragma unroll
    for (int i = 0; i < 4; ++i) {
      float av = xs[r0 + i][k];
      acc2[i][0] = fmaf(av, w0, acc2[i][0]);
      acc2[i][1] = fmaf(av, w1v, acc2[i][1]);
      acc2[i][2] = fmaf(av, w2v, acc2[i][2]);
      acc2[i][3] = fmaf(av, w3v, acc2[i][3]);
    }
  }
#pragma unroll
  for (int i = 0; i < 4; ++i) {
    long rg = rbase + r0 + i;
    if (rg < nrows) {
#pragma unroll
      for (int j = 0; j < 4; ++j) out[rg * 64 + c0 + j] = acc2[i][j];
    }
  }
}

// ---------------------------------------------------------------------------
extern "C" void kernel_launch(void* const* d_in, const int* in_sizes, int n_in,
                              void* d_out, int out_size, void* d_ws, size_t ws_size,
                              hipStream_t stream) {
  const int N = in_sizes[1] / 3;
  const int G = in_sizes[2] / 3;
  const long E = (long)in_sizes[4] / 2;
  const int NB2 = (G + 255) / 256;           // <= 256 (G <= 65536)
  const int nodeBlocks = (N + 63) / 64;

  char* ws = (char*)d_ws;
  float* sums = (float*)ws;
  size_t off = (size_t)G * 256;
  int* cnt = (int*)(ws + off);     off += (size_t)G * 4;
  int* cursor = (int*)(ws + off);  off += (size_t)G * 4;
  int* bsum = (int*)(ws + off);    off += 1024;
  int* evp = (int*)(ws + off);     off += 256;
  unsigned int* pkS = (unsigned int*)(ws + off); off += (size_t)E * 4;
  u16* h_node = (u16*)(ws + off);  off += (size_t)N * 128;
  u16* img = (u16*)(ws + off);     off += (size_t)IMG_TOTAL * 2;
  float* fw = (float*)(ws + off);

  // zero sums + cnt (ws poisoned 0xAA before every timed launch)
  hipMemsetAsync(ws, 0, (size_t)G * 260, stream);

  Ptrs a;
  const int map[20] = {0,1,2,3, 5,6,7,8, 9,10,11,12, 13,14,15,16, 17,18,19,20};
  for (int i = 0; i < 20; ++i) a.p[i] = d_in[map[i]];

  fused_a<<<nodeBlocks + PREP_BLOCKS + HIST_BLOCKS, 256, 0, stream>>>(
      a, img, fw, (const int*)d_in[4], cnt, d_in[0], h_node, N, E, G, nodeBlocks);
  scan_k<<<NB2, 256, 0, stream>>>(cnt, cursor, bsum, G);
  scat_k<<<1024, 256, 0, stream>>>((const int*)d_in[4], cursor, bsum, pkS, evp, E, G, NB2);
  edge_kernel<<<(int)((E + ETILES * 64 - 1) / (ETILES * 64)), 256, 0, stream>>>(
      d_in[1], d_in[2], d_in[3], pkS, evp, h_node, img, fw, sums, G);
  upd_mlp<<<(G + 63) / 64, 256, 0, stream>>>(sums, cnt, fw, (float*)d_out, G);
}

// Round 9
// 474.355 us; speedup vs baseline: 1.1502x; 1.0287x over previous
//
#include <hip/hip_runtime.h>
#include <hip/hip_bf16.h>
#include <cstdint>

typedef __attribute__((ext_vector_type(8))) short short8;
typedef __attribute__((ext_vector_type(4))) float f32x4;
typedef unsigned short u16;

__device__ __forceinline__ float b2f(u16 u) {
  union { unsigned int i; float f; } v; v.i = ((unsigned int)u) << 16; return v.f;
}
// hardware RNE f32->bf16
__device__ __forceinline__ u16 f2b(float f) {
  __hip_bfloat16 h = __float2bfloat16(f);
  union { __hip_bfloat16 h; u16 u; } v; v.h = h; return v.u;
}
__device__ __forceinline__ float silu_f(float x) { return x / (1.0f + __expf(-x)); }

__device__ __forceinline__ float loadF(const void* p, long i, int isf32) {
  if (isf32) return ((const float*)p)[i];
  return b2f(((const u16*)p)[i]);
}

// dtype sniff bit: f32 data viewed as u16 -> low halves have uniform-random
// "bf16 exponent field": ~50% land outside [2^-63, 2^65). Genuine bf16
// N(0,1)/uniform data: none (zeros excluded).
__device__ __forceinline__ int sniffbit(u16 u) {
  unsigned e = (u >> 7) & 0xffu;
  return (e >= 0xC0u || (e < 0x40u && (u & 0x7fffu) != 0)) ? 1 : 0;
}

struct Ptrs { const void* p[20]; int n[20]; };

// f32 prepped-weight layout (float offsets)
#define FW_EW1 0
#define FW_UW1 384
#define FW_UW2 4480
#define FW_UB1 8576
#define FW_UB2 8640
#define FW_EB1 8704
#define FW_EB2 8768
#define FW_MB1 8832
#define FW_MB2 8896
#define FW_TOTAL 8960

// bf16 transposed image layout (u16 offsets)
#define IMG_EW2 0
#define IMG_MW1 4608
#define IMG_MW2 13312
#define IMG_TOTAL 17920

#define PREP_BLOCKS 105   // ceil((IMG_TOTAL + FW_TOTAL)/256)
#define HIST_BLOCKS 1024

// ---------------------------------------------------------------------------
// Kernel 0: per-tensor dtype detection (once, 20 blocks) -> flags[0..19].
// ---------------------------------------------------------------------------
__global__ __launch_bounds__(256) void detect_k(Ptrs a, int* flags) {
  int j = blockIdx.x;
  const u16* q = (const u16*)a.p[j];
  int n = a.n[j];
  int m = n < 4096 ? n : 4096;    // first n u16s in-bounds for either dtype
  int cnt = 0;
  for (int i = threadIdx.x; i < m; i += 256) cnt += sniffbit(q[i]);
  __shared__ int tot;
  if (threadIdx.x == 0) tot = 0;
  __syncthreads();
  if (cnt) atomicAdd(&tot, cnt);
  __syncthreads();
  if (threadIdx.x == 0) flags[j] = (tot >= 2) ? 1 : 0;
}

// ---------------------------------------------------------------------------
// Kernel 1: histogram | weight prep | node MLP (independent; hist first so
// its long-latency atomics start early; node is the long pole, runs last).
// ---------------------------------------------------------------------------
__global__ __launch_bounds__(256) void fused_a(
    Ptrs a, const int* __restrict__ flags,
    u16* __restrict__ img, float* __restrict__ fw,
    const int* __restrict__ eidx, int* __restrict__ cnt,
    u16* __restrict__ hout, int nrows, long E, int G)
{
  const int t = threadIdx.x;
  const int b = blockIdx.x;

  if (b < HIST_BLOCKS) {
    // ---- histogram ----
    long i = (long)b * 256 + t;
    const long stride = (long)HIST_BLOCKS * 256;
    for (; i < E; i += stride) {
      int tg = eidx[E + i];
      if (tg >= 0 && tg < G) atomicAdd(&cnt[tg], 1);
    }
    return;
  }

  if (b < HIST_BLOCKS + PREP_BLOCKS) {
    // ---- weight prep (transposed bf16 image + f32 ew1/upd/biases) ----
    int i = (b - HIST_BLOCKS) * 256 + t;
    if (i < IMG_TOTAL) {
      const void* bp; int fl; long si; bool real;
      if (i < IMG_MW1) { int nn = i / 72, k = i % 72; bp = a.p[10]; fl = flags[10]; real = k < 64; si = (long)k * 64 + nn; }
      else if (i < IMG_MW2) { int t2 = i - IMG_MW1; int nn = t2 / 136, k = t2 % 136; bp = a.p[12]; fl = flags[12]; real = k < 128; si = (long)k * 64 + nn; }
      else { int t2 = i - IMG_MW2; int nn = t2 / 72, k = t2 % 72; bp = a.p[14]; fl = flags[14]; real = k < 64; si = (long)k * 64 + nn; }
      u16 val = 0;
      if (real) val = f2b(loadF(bp, si, fl));
      img[i] = val;
    } else if (i < IMG_TOTAL + FW_TOTAL) {
      int j = i - IMG_TOTAL;
      const void* bp; int fl; long si;
      if (j < 384)        { bp = a.p[8];  fl = flags[8];  si = j; }
      else if (j < 4480)  { bp = a.p[16]; fl = flags[16]; si = j - 384; }
      else if (j < 8576)  { bp = a.p[18]; fl = flags[18]; si = j - 4480; }
      else {
        int bb = j - 8576; int seg = bb >> 6; si = bb & 63;
        switch (seg) {
          case 0: bp = a.p[17]; fl = flags[17]; break;
          case 1: bp = a.p[19]; fl = flags[19]; break;
          case 2: bp = a.p[9];  fl = flags[9];  break;
          case 3: bp = a.p[11]; fl = flags[11]; break;
          case 4: bp = a.p[13]; fl = flags[13]; break;
          default: bp = a.p[15]; fl = flags[15]; break;
        }
      }
      fw[j] = loadF(bp, si, fl);
    }
    return;
  }

  // ---- node MLP (raw weights via flags) ----
  __shared__ float xs[64][68];
  __shared__ float w1s[64][68];
  __shared__ float w2s[64][68];
  __shared__ float b1s[64];
  __shared__ float b2s[64];
  const void* x = a.p[0];
  const int xf = flags[0], f1 = flags[4], fb1 = flags[5], f2 = flags[6], fb2 = flags[7];
  const long rbase = (long)(b - HIST_BLOCKS - PREP_BLOCKS) * 64;
  for (int i = t; i < 4096; i += 256) {
    int k = i >> 6, cc = i & 63;
    w1s[k][cc] = loadF(a.p[4], i, f1);
    w2s[k][cc] = loadF(a.p[6], i, f2);
  }
  if (t < 64) { b1s[t] = loadF(a.p[5], t, fb1); b2s[t] = loadF(a.p[7], t, fb2); }
  {
    int row = t >> 2, ch = t & 3;
    long rg = rbase + row;
    if (rg < nrows) {
      if (xf) {
        const float* xp = (const float*)x + rg * 64 + ch * 16;
#pragma unroll
        for (int m = 0; m < 16; ++m) xs[row][ch * 16 + m] = xp[m];
      } else {
        const u16* xp = (const u16*)x + rg * 64 + ch * 16;
#pragma unroll
        for (int m = 0; m < 16; ++m) xs[row][ch * 16 + m] = b2f(xp[m]);
      }
    } else {
#pragma unroll
      for (int m = 0; m < 16; ++m) xs[row][ch * 16 + m] = 0.f;
    }
  }
  __syncthreads();
  const int r0 = (t >> 4) * 4, c0 = (t & 15) * 4;
  float acc[4][4];
#pragma unroll
  for (int i = 0; i < 4; ++i)
#pragma unroll
    for (int j = 0; j < 4; ++j) acc[i][j] = b1s[c0 + j];
  for (int k = 0; k < 64; ++k) {
    float w0 = w1s[k][c0], w1v = w1s[k][c0 + 1], w2v = w1s[k][c0 + 2], w3v = w1s[k][c0 + 3];
#pragma unroll
    for (int i = 0; i < 4; ++i) {
      float av = xs[r0 + i][k];
      acc[i][0] = fmaf(av, w0, acc[i][0]);
      acc[i][1] = fmaf(av, w1v, acc[i][1]);
      acc[i][2] = fmaf(av, w2v, acc[i][2]);
      acc[i][3] = fmaf(av, w3v, acc[i][3]);
    }
  }
  __syncthreads();
#pragma unroll
  for (int i = 0; i < 4; ++i)
#pragma unroll
    for (int j = 0; j < 4; ++j) xs[r0 + i][c0 + j] = silu_f(acc[i][j]);
  __syncthreads();
  float acc2[4][4];
#pragma unroll
  for (int i = 0; i < 4; ++i)
#pragma unroll
    for (int j = 0; j < 4; ++j) acc2[i][j] = b2s[c0 + j];
  for (int k = 0; k < 64; ++k) {
    float w0 = w2s[k][c0], w1v = w2s[k][c0 + 1], w2v = w2s[k][c0 + 2], w3v = w2s[k][c0 + 3];
#pragma unroll
    for (int i = 0; i < 4; ++i) {
      float av = xs[r0 + i][k];
      acc2[i][0] = fmaf(av, w0, acc2[i][0]);
      acc2[i][1] = fmaf(av, w1v, acc2[i][1]);
      acc2[i][2] = fmaf(av, w2v, acc2[i][2]);
      acc2[i][3] = fmaf(av, w3v, acc2[i][3]);
    }
  }
#pragma unroll
  for (int i = 0; i < 4; ++i) {
    long rg = rbase + r0 + i;
    if (rg < nrows) {
#pragma unroll
      for (int j = 0; j < 4; ++j) hout[rg * 64 + c0 + j] = f2b(acc2[i][j]);
    }
  }
}

// ---------------------------------------------------------------------------
// Kernel 2: per-256-chunk exclusive scan of cnt -> cursor, chunk sums -> bsum.
// ---------------------------------------------------------------------------
__global__ __launch_bounds__(256) void scan_k(const int* __restrict__ cnt,
                                              int* __restrict__ cursor,
                                              int* __restrict__ bsum, int G) {
  __shared__ int sd[256];
  const int t = threadIdx.x;
  int i = blockIdx.x * 256 + t;
  int v = (i < G) ? cnt[i] : 0;
  sd[t] = v;
  __syncthreads();
  for (int off = 1; off < 256; off <<= 1) {
    int x2 = (t >= off) ? sd[t - off] : 0;
    __syncthreads();
    sd[t] += x2;
    __syncthreads();
  }
  if (i < G) cursor[i] = sd[t] - v;
  if (t == 255) bsum[blockIdx.x] = sd[255];
}

// ---------------------------------------------------------------------------
// Kernel 3: scatter into sorted order; inline top-level scan of bsum (<=256).
// pkS writes are nontemporal (scattered 4B stores; bypass write-allocate).
// pack: src (17 bits) | tgt<<17 (15 bits)
// ---------------------------------------------------------------------------
__global__ __launch_bounds__(256) void scat_k(const int* __restrict__ eidx,
                                              int* __restrict__ cursor,
                                              const int* __restrict__ bsum,
                                              unsigned int* __restrict__ pkS,
                                              int* __restrict__ evp,
                                              long E, int G, int NB2) {
  __shared__ int bo[256];
  const int t = threadIdx.x;
  int v = (t < NB2) ? bsum[t] : 0;
  bo[t] = v;
  __syncthreads();
  for (int off = 1; off < 256; off <<= 1) {
    int x2 = (t >= off) ? bo[t - off] : 0;
    __syncthreads();
    bo[t] += x2;
    __syncthreads();
  }
  if (blockIdx.x == 0 && t == 0) *evp = bo[NB2 - 1];
  int excl = bo[t] - v;
  __syncthreads();
  bo[t] = excl;
  __syncthreads();
  long i = (long)blockIdx.x * 256 + t;
  const long stride = (long)gridDim.x * 256;
  for (; i < E; i += stride) {
    int tg = eidx[E + i];
    if (tg >= 0 && tg < G) {
      int s = eidx[i];
      int p = atomicAdd(&cursor[tg], 1) + bo[tg >> 8];
      __builtin_nontemporal_store((unsigned int)s | ((unsigned int)tg << 17), pkS + p);
    }
  }
}

// ---------------------------------------------------------------------------
// Kernel 4: edge pipeline (block-tile, sorted edges). ETILES=8, 6 barriers
// per tile, no per-block sniff, no src_s (h_node loader decodes pkS).
// msgf overlays hA after S3 (~31 KB LDS, 5 blocks/CU).
// ---------------------------------------------------------------------------
#define ETILES 8

__global__ __launch_bounds__(256, 5) void edge_kernel(
    const void* node_pos, const void* grid_pos, const void* orient,
    const unsigned int* __restrict__ pkS, const int* __restrict__ evp,
    const u16* __restrict__ h_node, const u16* __restrict__ img,
    const float* __restrict__ fw, const int* __restrict__ flags,
    float* __restrict__ sums, int G)
{
  __shared__ __align__(16) u16 hA[64][136];    // msg_in; after S3 reused as msgf
  __shared__ __align__(16) u16 ef1[64][72];
  __shared__ float eaf[64][6];
  __shared__ float w1e[6][64];
  __shared__ float biasE[4][64];
  __shared__ int tgt_s[64];
  float (*msgf)[66] = (float (*)[66])&hA[0][0];   // 64*66*4 = 16896 <= 17408

  const int t = threadIdx.x;
  const int pf = flags[1], gf = flags[2], of = flags[3];
  const int Ev = *evp;
  for (int i = t; i < 384; i += 256) w1e[i / 64][i % 64] = fw[FW_EW1 + i];
  { int seg = t >> 6, cc = t & 63; biasE[seg][cc] = fw[FW_EB1 + seg * 64 + cc]; }
  __syncthreads();

  const int lane = t & 63, w = t >> 6;
  const int q = lane >> 4, c = lane & 15;
  const int m0 = w * 16;
  const u16* wE2 = img + IMG_EW2;
  const u16* wM1 = img + IMG_MW1;
  const u16* wM2 = img + IMG_MW2;
  const f32x4 z = {0.f, 0.f, 0.f, 0.f};

  for (int tile = 0; tile < ETILES; ++tile) {
    long base = ((long)blockIdx.x * ETILES + tile) * 64;
    if (base >= Ev) break;
    // gather: geometry (t<64) + h_node rows (all threads, pkS decoded inline)
    if (t < 64) {
      long eg = base + t;
      int s = 0, tg = -1;
      if (eg < Ev) {
        unsigned int pk = pkS[eg];
        s = (int)(pk & 0x1FFFFu);
        tg = (int)(pk >> 17);
      }
      tgt_s[t] = tg;
      int tgc = (tg >= 0) ? tg : 0;
      float ps[3], rel[3], tr[3];
#pragma unroll
      for (int i = 0; i < 3; ++i) {
        ps[i] = loadF(node_pos, (long)s * 3 + i, pf);
        rel[i] = loadF(grid_pos, (long)tgc * 3 + i, gf) - ps[i];
      }
#pragma unroll
      for (int j = 0; j < 3; ++j) tr[j] = 0.f;
#pragma unroll
      for (int i = 0; i < 3; ++i)
#pragma unroll
        for (int j = 0; j < 3; ++j)
          tr[j] = fmaf(rel[i], loadF(orient, (long)s * 9 + i * 3 + j, of), tr[j]);
      eaf[t][0] = ps[0]; eaf[t][1] = ps[1]; eaf[t][2] = ps[2];
      eaf[t][3] = tr[0]; eaf[t][4] = tr[1]; eaf[t][5] = tr[2];
    }
    {
      int e = t >> 2, ch = t & 3;
      long eg = base + e;
      int s = 0;
      if (eg < Ev) s = (int)(pkS[eg] & 0x1FFFFu);
      const u16* hp = h_node + (long)s * 64 + ch * 16;
      short8 v0 = *(const short8*)hp;
      short8 v1 = *(const short8*)(hp + 8);
      *(short8*)&hA[e][ch * 16] = v0;
      *(short8*)&hA[e][ch * 16 + 8] = v1;
    }
    __syncthreads();  // gather committed

    // S1: edge MLP layer1 (K=6) f32 VALU -> silu -> ef1 (bf16)
    {
      int e = t >> 2, c0 = (t & 3) * 16;
      float a0 = eaf[e][0], a1 = eaf[e][1], a2 = eaf[e][2];
      float a3 = eaf[e][3], a4 = eaf[e][4], a5 = eaf[e][5];
      __align__(16) u16 tmp[16];
#pragma unroll
      for (int j = 0; j < 16; ++j) {
        int cc = c0 + j;
        float acc = biasE[0][cc];
        acc = fmaf(a0, w1e[0][cc], acc);
        acc = fmaf(a1, w1e[1][cc], acc);
        acc = fmaf(a2, w1e[2][cc], acc);
        acc = fmaf(a3, w1e[3][cc], acc);
        acc = fmaf(a4, w1e[4][cc], acc);
        acc = fmaf(a5, w1e[5][cc], acc);
        tmp[j] = f2b(silu_f(acc));
      }
      *(short8*)&ef1[e][c0] = *(const short8*)tmp;
      *(short8*)&ef1[e][c0 + 8] = *(const short8*)(tmp + 8);
    }
    __syncthreads();
    // S2: edge MLP layer2 (K=64) -> hA cols 64..127
    {
      short8 a0 = *(const short8*)&ef1[m0 + c][q * 8];
      short8 a1 = *(const short8*)&ef1[m0 + c][32 + q * 8];
#pragma unroll
      for (int nt = 0; nt < 4; ++nt) {
        short8 b0 = *(const short8*)&wE2[(nt * 16 + c) * 72 + q * 8];
        short8 b1v = *(const short8*)&wE2[(nt * 16 + c) * 72 + 32 + q * 8];
        f32x4 acc = __builtin_amdgcn_mfma_f32_16x16x32_bf16(a0, b0, z, 0, 0, 0);
        acc = __builtin_amdgcn_mfma_f32_16x16x32_bf16(a1, b1v, acc, 0, 0, 0);
#pragma unroll
        for (int r = 0; r < 4; ++r) {
          int row = m0 + q * 4 + r, col = nt * 16 + c;
          hA[row][64 + col] = f2b(acc[r] + biasE[1][col]);
        }
      }
    }
    __syncthreads();
    // S3: msg MLP layer1 (K=128) -> silu -> ef1
    {
      short8 a0 = *(const short8*)&hA[m0 + c][q * 8];
      short8 a1 = *(const short8*)&hA[m0 + c][32 + q * 8];
      short8 a2 = *(const short8*)&hA[m0 + c][64 + q * 8];
      short8 a3 = *(const short8*)&hA[m0 + c][96 + q * 8];
#pragma unroll
      for (int nt = 0; nt < 4; ++nt) {
        const u16* wp = &wM1[(nt * 16 + c) * 136];
        f32x4 acc = __builtin_amdgcn_mfma_f32_16x16x32_bf16(a0, *(const short8*)(wp + q * 8), z, 0, 0, 0);
        acc = __builtin_amdgcn_mfma_f32_16x16x32_bf16(a1, *(const short8*)(wp + 32 + q * 8), acc, 0, 0, 0);
        acc = __builtin_amdgcn_mfma_f32_16x16x32_bf16(a2, *(const short8*)(wp + 64 + q * 8), acc, 0, 0, 0);
        acc = __builtin_amdgcn_mfma_f32_16x16x32_bf16(a3, *(const short8*)(wp + 96 + q * 8), acc, 0, 0, 0);
#pragma unroll
        for (int r = 0; r < 4; ++r) {
          int row = m0 + q * 4 + r, col = nt * 16 + c;
          ef1[row][col] = f2b(silu_f(acc[r] + biasE[2][col]));
        }
      }
    }
    __syncthreads();  // hA dead from here: msgf overlays it
    // S4: msg MLP layer2 (K=64) -> msgf (f32, +bias)
    {
      short8 a0 = *(const short8*)&ef1[m0 + c][q * 8];
      short8 a1 = *(const short8*)&ef1[m0 + c][32 + q * 8];
#pragma unroll
      for (int nt = 0; nt < 4; ++nt) {
        short8 b0 = *(const short8*)&wM2[(nt * 16 + c) * 72 + q * 8];
        short8 b1v = *(const short8*)&wM2[(nt * 16 + c) * 72 + 32 + q * 8];
        f32x4 acc = __builtin_amdgcn_mfma_f32_16x16x32_bf16(a0, b0, z, 0, 0, 0);
        acc = __builtin_amdgcn_mfma_f32_16x16x32_bf16(a1, b1v, acc, 0, 0, 0);
#pragma unroll
        for (int r = 0; r < 4; ++r) {
          int row = m0 + q * 4 + r, col = nt * 16 + c;
          msgf[row][col] = acc[r] + biasE[3][col];
        }
      }
    }
    __syncthreads();
    // Run-reduction: wave w walks rows [16w,16w+16), col = lane.
    // Interior runs plain-store (sole writer), boundary runs atomicAdd.
    {
      int col = lane;
      int r0 = w * 16;
      int cur = tgt_s[r0];
      float run = msgf[r0][col];
      bool lopen = (r0 == 0) ? true : (tgt_s[r0 - 1] == cur);
#pragma unroll
      for (int r2 = 1; r2 < 16; ++r2) {
        int r = r0 + r2;
        int tg = tgt_s[r];
        float v = msgf[r][col];
        if (tg == cur) {
          run += v;
        } else {
          if (cur >= 0) {
            if (lopen) unsafeAtomicAdd(&sums[(long)cur * 64 + col], run);
            else sums[(long)cur * 64 + col] = run;
          }
          cur = tg; run = v; lopen = false;
        }
      }
      bool ropen = (r0 + 16 >= 64) ? true : (tgt_s[r0 + 16] == cur);
      if (cur >= 0) {
        if (lopen || ropen) unsafeAtomicAdd(&sums[(long)cur * 64 + col], run);
        else sums[(long)cur * 64 + col] = run;
      }
    }
    __syncthreads();  // msgf/tgt_s consumed; next tile may overwrite
  }
}

// ---------------------------------------------------------------------------
// Kernel 5: scatter-mean + update MLP (f32) -> f32 out [G,64]
// ---------------------------------------------------------------------------
__global__ __launch_bounds__(256) void upd_mlp(
    const float* __restrict__ sums, const int* __restrict__ cnt,
    const float* __restrict__ fw, float* __restrict__ out, int nrows)
{
  __shared__ float xs[64][68];
  __shared__ float w1s[64][68];
  __shared__ float w2s[64][68];
  __shared__ float b1s[64];
  __shared__ float b2s[64];
  const int t = threadIdx.x;
  const long rbase = (long)blockIdx.x * 64;
  for (int i = t; i < 4096; i += 256) {
    int k = i >> 6, cc = i & 63;
    w1s[k][cc] = fw[FW_UW1 + i];
    w2s[k][cc] = fw[FW_UW2 + i];
  }
  if (t < 64) { b1s[t] = fw[FW_UB1 + t]; b2s[t] = fw[FW_UB2 + t]; }
  {
    int row = t >> 2, ch = t & 3;
    long rg = rbase + row;
    if (rg < nrows) {
      float inv = 1.0f / fmaxf((float)cnt[rg], 1.0f);
      const float* p = sums + rg * 64 + ch * 16;
#pragma unroll
      for (int m = 0; m < 16; ++m) xs[row][ch * 16 + m] = p[m] * inv;
    } else {
#pragma unroll
      for (int m = 0; m < 16; ++m) xs[row][ch * 16 + m] = 0.f;
    }
  }
  __syncthreads();
  const int r0 = (t >> 4) * 4, c0 = (t & 15) * 4;
  float acc[4][4];
#pragma unroll
  for (int i = 0; i < 4; ++i)
#pragma unroll
    for (int j = 0; j < 4; ++j) acc[i][j] = b1s[c0 + j];
  for (int k = 0; k < 64; ++k) {
    float w0 = w1s[k][c0], w1v = w1s[k][c0 + 1], w2v = w1s[k][c0 + 2], w3v = w1s[k][c0 + 3];
#pragma unroll
    for (int i = 0; i < 4; ++i) {
      float av = xs[r0 + i][k];
      acc[i][0] = fmaf(av, w0, acc[i][0]);
      acc[i][1] = fmaf(av, w1v, acc[i][1]);
      acc[i][2] = fmaf(av, w2v, acc[i][2]);
      acc[i][3] = fmaf(av, w3v, acc[i][3]);
    }
  }
  __syncthreads();
#pragma unroll
  for (int i = 0; i < 4; ++i)
#pragma unroll
    for (int j = 0; j < 4; ++j) xs[r0 + i][c0 + j] = silu_f(acc[i][j]);
  __syncthreads();
  float acc2[4][4];
#pragma unroll
  for (int i = 0; i < 4; ++i)
#pragma unroll
    for (int j = 0; j < 4; ++j) acc2[i][j] = b2s[c0 + j];
  for (int k = 0; k < 64; ++k) {
    float w0 = w2s[k][c0], w1v = w2s[k][c0 + 1], w2v = w2s[k][c0 + 2], w3v = w2s[k][c0 + 3];
#pragma unroll
    for (int i = 0; i < 4; ++i) {
      float av = xs[r0 + i][k];
      acc2[i][0] = fmaf(av, w0, acc2[i][0]);
      acc2[i][1] = fmaf(av, w1v, acc2[i][1]);
      acc2[i][2] = fmaf(av, w2v, acc2[i][2]);
      acc2[i][3] = fmaf(av, w3v, acc2[i][3]);
    }
  }
#pragma unroll
  for (int i = 0; i < 4; ++i) {
    long rg = rbase + r0 + i;
    if (rg < nrows) {
#pragma unroll
      for (int j = 0; j < 4; ++j) out[rg * 64 + c0 + j] = acc2[i][j];
    }
  }
}

// ---------------------------------------------------------------------------
extern "C" void kernel_launch(void* const* d_in, const int* in_sizes, int n_in,
                              void* d_out, int out_size, void* d_ws, size_t ws_size,
                              hipStream_t stream) {
  const int N = in_sizes[1] / 3;
  const int G = in_sizes[2] / 3;
  const long E = (long)in_sizes[4] / 2;
  const int NB2 = (G + 255) / 256;           // <= 256 (G <= 65536)
  const int nodeBlocks = (N + 63) / 64;

  char* ws = (char*)d_ws;
  float* sums = (float*)ws;
  size_t off = (size_t)G * 256;
  int* cnt = (int*)(ws + off);     off += (size_t)G * 4;
  int* cursor = (int*)(ws + off);  off += (size_t)G * 4;
  int* bsum = (int*)(ws + off);    off += 1024;
  int* evp = (int*)(ws + off);     off += 256;
  int* flags = (int*)(ws + off);   off += 256;
  unsigned int* pkS = (unsigned int*)(ws + off); off += (size_t)E * 4;
  u16* h_node = (u16*)(ws + off);  off += (size_t)N * 128;
  u16* img = (u16*)(ws + off);     off += (size_t)IMG_TOTAL * 2;
  float* fw = (float*)(ws + off);

  // zero sums + cnt (ws poisoned 0xAA before every timed launch)
  hipMemsetAsync(ws, 0, (size_t)G * 260, stream);

  Ptrs a;
  const int map[20] = {0,1,2,3, 5,6,7,8, 9,10,11,12, 13,14,15,16, 17,18,19,20};
  for (int i = 0; i < 20; ++i) { a.p[i] = d_in[map[i]]; a.n[i] = in_sizes[map[i]]; }

  detect_k<<<20, 256, 0, stream>>>(a, flags);
  fused_a<<<HIST_BLOCKS + PREP_BLOCKS + nodeBlocks, 256, 0, stream>>>(
      a, flags, img, fw, (const int*)d_in[4], cnt, h_node, N, E, G);
  scan_k<<<NB2, 256, 0, stream>>>(cnt, cursor, bsum, G);
  scat_k<<<1024, 256, 0, stream>>>((const int*)d_in[4], cursor, bsum, pkS, evp, E, G, NB2);
  edge_kernel<<<(int)((E + ETILES * 64 - 1) / (ETILES * 64)), 256, 0, stream>>>(
      d_in[1], d_in[2], d_in[3], pkS, evp, h_node, img, fw, flags, sums, G);
  upd_mlp<<<(G + 63) / 64, 256, 0, stream>>>(sums, cnt, fw, (float*)d_out, G);
}

// Round 10
// 463.470 us; speedup vs baseline: 1.1772x; 1.0235x over previous
//
#include <hip/hip_runtime.h>
#include <hip/hip_bf16.h>
#include <cstdint>

typedef __attribute__((ext_vector_type(8))) short short8;
typedef __attribute__((ext_vector_type(4))) float f32x4;
typedef unsigned short u16;

__device__ __forceinline__ float b2f(u16 u) {
  union { unsigned int i; float f; } v; v.i = ((unsigned int)u) << 16; return v.f;
}
// hardware RNE f32->bf16
__device__ __forceinline__ u16 f2b(float f) {
  __hip_bfloat16 h = __float2bfloat16(f);
  union { __hip_bfloat16 h; u16 u; } v; v.h = h; return v.u;
}
__device__ __forceinline__ float silu_f(float x) { return x / (1.0f + __expf(-x)); }

__device__ __forceinline__ float loadF(const void* p, long i, int isf32) {
  if (isf32) return ((const float*)p)[i];
  return b2f(((const u16*)p)[i]);
}

// dtype sniff bit: f32 data viewed as u16 -> low halves have uniform-random
// "bf16 exponent field": ~50% land outside [2^-63, 2^65). Genuine bf16
// N(0,1)/uniform data: none (zeros excluded).
__device__ __forceinline__ int sniffbit(u16 u) {
  unsigned e = (u >> 7) & 0xffu;
  return (e >= 0xC0u || (e < 0x40u && (u & 0x7fffu) != 0)) ? 1 : 0;
}

struct Ptrs { const void* p[20]; int n[20]; };

// f32 prepped-weight layout (float offsets)
#define FW_EW1 0
#define FW_UW1 384
#define FW_UW2 4480
#define FW_UB1 8576
#define FW_UB2 8640
#define FW_EB1 8704
#define FW_EB2 8768
#define FW_MB1 8832
#define FW_MB2 8896
#define FW_TOTAL 8960

// bf16 transposed image layout (u16 offsets)
#define IMG_EW2 0
#define IMG_MW1 4608
#define IMG_MW2 13312
#define IMG_TOTAL 17920

#define PREP_BLOCKS 105   // ceil((IMG_TOTAL + FW_TOTAL)/256)
#define HIST_BLOCKS 1024

// ---------------------------------------------------------------------------
// Kernel 0: per-tensor dtype detection (once, 20 blocks) -> flags[0..19].
// ---------------------------------------------------------------------------
__global__ __launch_bounds__(256) void detect_k(Ptrs a, int* flags) {
  int j = blockIdx.x;
  const u16* q = (const u16*)a.p[j];
  int n = a.n[j];
  int m = n < 4096 ? n : 4096;
  int cnt = 0;
  for (int i = threadIdx.x; i < m; i += 256) cnt += sniffbit(q[i]);
  __shared__ int tot;
  if (threadIdx.x == 0) tot = 0;
  __syncthreads();
  if (cnt) atomicAdd(&tot, cnt);
  __syncthreads();
  if (threadIdx.x == 0) flags[j] = (tot >= 2) ? 1 : 0;
}

// ---------------------------------------------------------------------------
// Kernel 1: histogram (XCD-sharded) | weight prep | node MLP.
// cnt8 layout: [shard c][G] with c = blockIdx&7 -> atomics stay on-shard.
// ---------------------------------------------------------------------------
__global__ __launch_bounds__(256) void fused_a(
    Ptrs a, const int* __restrict__ flags,
    u16* __restrict__ img, float* __restrict__ fw,
    const int* __restrict__ eidx, int* __restrict__ cnt8,
    u16* __restrict__ hout, int nrows, long E, int G)
{
  const int t = threadIdx.x;
  const int b = blockIdx.x;

  if (b < HIST_BLOCKS) {
    // ---- histogram into shard (b&7) ----
    int* cs = cnt8 + (size_t)(b & 7) * G;
    long i = (long)b * 256 + t;
    const long stride = (long)HIST_BLOCKS * 256;
    for (; i < E; i += stride) {
      int tg = eidx[E + i];
      if (tg >= 0 && tg < G) atomicAdd(&cs[tg], 1);
    }
    return;
  }

  if (b < HIST_BLOCKS + PREP_BLOCKS) {
    // ---- weight prep (transposed bf16 image + f32 ew1/upd/biases) ----
    int i = (b - HIST_BLOCKS) * 256 + t;
    if (i < IMG_TOTAL) {
      const void* bp; int fl; long si; bool real;
      if (i < IMG_MW1) { int nn = i / 72, k = i % 72; bp = a.p[10]; fl = flags[10]; real = k < 64; si = (long)k * 64 + nn; }
      else if (i < IMG_MW2) { int t2 = i - IMG_MW1; int nn = t2 / 136, k = t2 % 136; bp = a.p[12]; fl = flags[12]; real = k < 128; si = (long)k * 64 + nn; }
      else { int t2 = i - IMG_MW2; int nn = t2 / 72, k = t2 % 72; bp = a.p[14]; fl = flags[14]; real = k < 64; si = (long)k * 64 + nn; }
      u16 val = 0;
      if (real) val = f2b(loadF(bp, si, fl));
      img[i] = val;
    } else if (i < IMG_TOTAL + FW_TOTAL) {
      int j = i - IMG_TOTAL;
      const void* bp; int fl; long si;
      if (j < 384)        { bp = a.p[8];  fl = flags[8];  si = j; }
      else if (j < 4480)  { bp = a.p[16]; fl = flags[16]; si = j - 384; }
      else if (j < 8576)  { bp = a.p[18]; fl = flags[18]; si = j - 4480; }
      else {
        int bb = j - 8576; int seg = bb >> 6; si = bb & 63;
        switch (seg) {
          case 0: bp = a.p[17]; fl = flags[17]; break;
          case 1: bp = a.p[19]; fl = flags[19]; break;
          case 2: bp = a.p[9];  fl = flags[9];  break;
          case 3: bp = a.p[11]; fl = flags[11]; break;
          case 4: bp = a.p[13]; fl = flags[13]; break;
          default: bp = a.p[15]; fl = flags[15]; break;
        }
      }
      fw[j] = loadF(bp, si, fl);
    }
    return;
  }

  // ---- node MLP (raw weights via flags) ----
  __shared__ float xs[64][68];
  __shared__ float w1s[64][68];
  __shared__ float w2s[64][68];
  __shared__ float b1s[64];
  __shared__ float b2s[64];
  const void* x = a.p[0];
  const int xf = flags[0], f1 = flags[4], fb1 = flags[5], f2 = flags[6], fb2 = flags[7];
  const long rbase = (long)(b - HIST_BLOCKS - PREP_BLOCKS) * 64;
  for (int i = t; i < 4096; i += 256) {
    int k = i >> 6, cc = i & 63;
    w1s[k][cc] = loadF(a.p[4], i, f1);
    w2s[k][cc] = loadF(a.p[6], i, f2);
  }
  if (t < 64) { b1s[t] = loadF(a.p[5], t, fb1); b2s[t] = loadF(a.p[7], t, fb2); }
  {
    int row = t >> 2, ch = t & 3;
    long rg = rbase + row;
    if (rg < nrows) {
      if (xf) {
        const float* xp = (const float*)x + rg * 64 + ch * 16;
#pragma unroll
        for (int m = 0; m < 16; ++m) xs[row][ch * 16 + m] = xp[m];
      } else {
        const u16* xp = (const u16*)x + rg * 64 + ch * 16;
#pragma unroll
        for (int m = 0; m < 16; ++m) xs[row][ch * 16 + m] = b2f(xp[m]);
      }
    } else {
#pragma unroll
      for (int m = 0; m < 16; ++m) xs[row][ch * 16 + m] = 0.f;
    }
  }
  __syncthreads();
  const int r0 = (t >> 4) * 4, c0 = (t & 15) * 4;
  float acc[4][4];
#pragma unroll
  for (int i = 0; i < 4; ++i)
#pragma unroll
    for (int j = 0; j < 4; ++j) acc[i][j] = b1s[c0 + j];
  for (int k = 0; k < 64; ++k) {
    float w0 = w1s[k][c0], w1v = w1s[k][c0 + 1], w2v = w1s[k][c0 + 2], w3v = w1s[k][c0 + 3];
#pragma unroll
    for (int i = 0; i < 4; ++i) {
      float av = xs[r0 + i][k];
      acc[i][0] = fmaf(av, w0, acc[i][0]);
      acc[i][1] = fmaf(av, w1v, acc[i][1]);
      acc[i][2] = fmaf(av, w2v, acc[i][2]);
      acc[i][3] = fmaf(av, w3v, acc[i][3]);
    }
  }
  __syncthreads();
#pragma unroll
  for (int i = 0; i < 4; ++i)
#pragma unroll
    for (int j = 0; j < 4; ++j) xs[r0 + i][c0 + j] = silu_f(acc[i][j]);
  __syncthreads();
  float acc2[4][4];
#pragma unroll
  for (int i = 0; i < 4; ++i)
#pragma unroll
    for (int j = 0; j < 4; ++j) acc2[i][j] = b2s[c0 + j];
  for (int k = 0; k < 64; ++k) {
    float w0 = w2s[k][c0], w1v = w2s[k][c0 + 1], w2v = w2s[k][c0 + 2], w3v = w2s[k][c0 + 3];
#pragma unroll
    for (int i = 0; i < 4; ++i) {
      float av = xs[r0 + i][k];
      acc2[i][0] = fmaf(av, w0, acc2[i][0]);
      acc2[i][1] = fmaf(av, w1v, acc2[i][1]);
      acc2[i][2] = fmaf(av, w2v, acc2[i][2]);
      acc2[i][3] = fmaf(av, w3v, acc2[i][3]);
    }
  }
#pragma unroll
  for (int i = 0; i < 4; ++i) {
    long rg = rbase + r0 + i;
    if (rg < nrows) {
#pragma unroll
      for (int j = 0; j < 4; ++j) hout[rg * 64 + c0 + j] = f2b(acc2[i][j]);
    }
  }
}

// ---------------------------------------------------------------------------
// Kernel 2: exclusive scan over the 8G (tg,c) pairs in TARGET-MAJOR order
// (j = tg*8 + c, value at cnt8[c*G+tg]). 1024 elems/block, 256 blocks max.
// Writes per-pair local prefix into cursor8[c*G+tg]; chunk sums into bsum.
// ---------------------------------------------------------------------------
__global__ __launch_bounds__(256) void scan_k(const int* __restrict__ cnt8,
                                              int* __restrict__ cursor8,
                                              int* __restrict__ bsum, int G) {
  __shared__ int sd[256];
  const int t = threadIdx.x;
  const long tot = 8L * G;
  long j0 = (long)blockIdx.x * 1024 + (long)t * 4;
  int v[4];
#pragma unroll
  for (int k = 0; k < 4; ++k) {
    long j = j0 + k;
    v[k] = (j < tot) ? cnt8[(size_t)(j & 7) * G + (j >> 3)] : 0;
  }
  int local = v[0] + v[1] + v[2] + v[3];
  sd[t] = local;
  __syncthreads();
  for (int off = 1; off < 256; off <<= 1) {
    int x2 = (t >= off) ? sd[t - off] : 0;
    __syncthreads();
    sd[t] += x2;
    __syncthreads();
  }
  int p = sd[t] - local;
#pragma unroll
  for (int k = 0; k < 4; ++k) {
    long j = j0 + k;
    if (j < tot) cursor8[(size_t)(j & 7) * G + (j >> 3)] = p;
    p += v[k];
  }
  if (t == 255) bsum[blockIdx.x] = sd[255];
}

// ---------------------------------------------------------------------------
// Kernel 3: scatter into sorted order, XCD-sharded cursors (c = blockIdx&7);
// inline top-level scan of bsum (<=256 chunks). NT stores for pkS.
// pack: src (17 bits) | tgt<<17 (15 bits)
// ---------------------------------------------------------------------------
__global__ __launch_bounds__(256) void scat_k(const int* __restrict__ eidx,
                                              int* __restrict__ cursor8,
                                              const int* __restrict__ bsum,
                                              unsigned int* __restrict__ pkS,
                                              int* __restrict__ evp,
                                              long E, int G, int NB2) {
  __shared__ int bo[256];
  const int t = threadIdx.x;
  int v = (t < NB2) ? bsum[t] : 0;
  bo[t] = v;
  __syncthreads();
  for (int off = 1; off < 256; off <<= 1) {
    int x2 = (t >= off) ? bo[t - off] : 0;
    __syncthreads();
    bo[t] += x2;
    __syncthreads();
  }
  if (blockIdx.x == 0 && t == 0) *evp = bo[NB2 - 1];
  int excl = bo[t] - v;
  __syncthreads();
  bo[t] = excl;
  __syncthreads();
  const int c = blockIdx.x & 7;
  int* cur = cursor8 + (size_t)c * G;
  long i = (long)blockIdx.x * 256 + t;
  const long stride = (long)gridDim.x * 256;
  for (; i < E; i += stride) {
    int tg = eidx[E + i];
    if (tg >= 0 && tg < G) {
      int s = eidx[i];
      long j = ((long)tg << 3) | c;
      int p = atomicAdd(&cur[tg], 1) + bo[j >> 10];
      __builtin_nontemporal_store((unsigned int)s | ((unsigned int)tg << 17), pkS + p);
    }
  }
}

// ---------------------------------------------------------------------------
// Kernel 4: edge pipeline (block-tile, sorted edges). ETILES=4 (best measured
// block-count/residency balance), merged gather, 6 barriers/tile.
// msgf overlays hA after S3 (~31 KB LDS, 5 blocks/CU).
// ---------------------------------------------------------------------------
#define ETILES 4

__global__ __launch_bounds__(256, 5) void edge_kernel(
    const void* node_pos, const void* grid_pos, const void* orient,
    const unsigned int* __restrict__ pkS, const int* __restrict__ evp,
    const u16* __restrict__ h_node, const u16* __restrict__ img,
    const float* __restrict__ fw, const int* __restrict__ flags,
    float* __restrict__ sums, int G)
{
  __shared__ __align__(16) u16 hA[64][136];    // msg_in; after S3 reused as msgf
  __shared__ __align__(16) u16 ef1[64][72];
  __shared__ float eaf[64][6];
  __shared__ float w1e[6][64];
  __shared__ float biasE[4][64];
  __shared__ int tgt_s[64];
  float (*msgf)[66] = (float (*)[66])&hA[0][0];   // 64*66*4 = 16896 <= 17408

  const int t = threadIdx.x;
  const int pf = flags[1], gf = flags[2], of = flags[3];
  const int Ev = *evp;
  for (int i = t; i < 384; i += 256) w1e[i / 64][i % 64] = fw[FW_EW1 + i];
  { int seg = t >> 6, cc = t & 63; biasE[seg][cc] = fw[FW_EB1 + seg * 64 + cc]; }
  __syncthreads();

  const int lane = t & 63, w = t >> 6;
  const int q = lane >> 4, c = lane & 15;
  const int m0 = w * 16;
  const u16* wE2 = img + IMG_EW2;
  const u16* wM1 = img + IMG_MW1;
  const u16* wM2 = img + IMG_MW2;
  const f32x4 z = {0.f, 0.f, 0.f, 0.f};

  for (int tile = 0; tile < ETILES; ++tile) {
    long base = ((long)blockIdx.x * ETILES + tile) * 64;
    if (base >= Ev) break;
    // gather: geometry (t<64) + h_node rows (all threads, pkS decoded inline)
    if (t < 64) {
      long eg = base + t;
      int s = 0, tg = -1;
      if (eg < Ev) {
        unsigned int pk = pkS[eg];
        s = (int)(pk & 0x1FFFFu);
        tg = (int)(pk >> 17);
      }
      tgt_s[t] = tg;
      int tgc = (tg >= 0) ? tg : 0;
      float ps[3], rel[3], tr[3];
#pragma unroll
      for (int i = 0; i < 3; ++i) {
        ps[i] = loadF(node_pos, (long)s * 3 + i, pf);
        rel[i] = loadF(grid_pos, (long)tgc * 3 + i, gf) - ps[i];
      }
#pragma unroll
      for (int j = 0; j < 3; ++j) tr[j] = 0.f;
#pragma unroll
      for (int i = 0; i < 3; ++i)
#pragma unroll
        for (int j = 0; j < 3; ++j)
          tr[j] = fmaf(rel[i], loadF(orient, (long)s * 9 + i * 3 + j, of), tr[j]);
      eaf[t][0] = ps[0]; eaf[t][1] = ps[1]; eaf[t][2] = ps[2];
      eaf[t][3] = tr[0]; eaf[t][4] = tr[1]; eaf[t][5] = tr[2];
    }
    {
      int e = t >> 2, ch = t & 3;
      long eg = base + e;
      int s = 0;
      if (eg < Ev) s = (int)(pkS[eg] & 0x1FFFFu);
      const u16* hp = h_node + (long)s * 64 + ch * 16;
      short8 v0 = *(const short8*)hp;
      short8 v1 = *(const short8*)(hp + 8);
      *(short8*)&hA[e][ch * 16] = v0;
      *(short8*)&hA[e][ch * 16 + 8] = v1;
    }
    __syncthreads();  // gather committed

    // S1: edge MLP layer1 (K=6) f32 VALU -> silu -> ef1 (bf16)
    {
      int e = t >> 2, c0 = (t & 3) * 16;
      float a0 = eaf[e][0], a1 = eaf[e][1], a2 = eaf[e][2];
      float a3 = eaf[e][3], a4 = eaf[e][4], a5 = eaf[e][5];
      __align__(16) u16 tmp[16];
#pragma unroll
      for (int j = 0; j < 16; ++j) {
        int cc = c0 + j;
        float acc = biasE[0][cc];
        acc = fmaf(a0, w1e[0][cc], acc);
        acc = fmaf(a1, w1e[1][cc], acc);
        acc = fmaf(a2, w1e[2][cc], acc);
        acc = fmaf(a3, w1e[3][cc], acc);
        acc = fmaf(a4, w1e[4][cc], acc);
        acc = fmaf(a5, w1e[5][cc], acc);
        tmp[j] = f2b(silu_f(acc));
      }
      *(short8*)&ef1[e][c0] = *(const short8*)tmp;
      *(short8*)&ef1[e][c0 + 8] = *(const short8*)(tmp + 8);
    }
    __syncthreads();
    // S2: edge MLP layer2 (K=64) -> hA cols 64..127
    {
      short8 a0 = *(const short8*)&ef1[m0 + c][q * 8];
      short8 a1 = *(const short8*)&ef1[m0 + c][32 + q * 8];
#pragma unroll
      for (int nt = 0; nt < 4; ++nt) {
        short8 b0 = *(const short8*)&wE2[(nt * 16 + c) * 72 + q * 8];
        short8 b1v = *(const short8*)&wE2[(nt * 16 + c) * 72 + 32 + q * 8];
        f32x4 acc = __builtin_amdgcn_mfma_f32_16x16x32_bf16(a0, b0, z, 0, 0, 0);
        acc = __builtin_amdgcn_mfma_f32_16x16x32_bf16(a1, b1v, acc, 0, 0, 0);
#pragma unroll
        for (int r = 0; r < 4; ++r) {
          int row = m0 + q * 4 + r, col = nt * 16 + c;
          hA[row][64 + col] = f2b(acc[r] + biasE[1][col]);
        }
      }
    }
    __syncthreads();
    // S3: msg MLP layer1 (K=128) -> silu -> ef1
    {
      short8 a0 = *(const short8*)&hA[m0 + c][q * 8];
      short8 a1 = *(const short8*)&hA[m0 + c][32 + q * 8];
      short8 a2 = *(const short8*)&hA[m0 + c][64 + q * 8];
      short8 a3 = *(const short8*)&hA[m0 + c][96 + q * 8];
#pragma unroll
      for (int nt = 0; nt < 4; ++nt) {
        const u16* wp = &wM1[(nt * 16 + c) * 136];
        f32x4 acc = __builtin_amdgcn_mfma_f32_16x16x32_bf16(a0, *(const short8*)(wp + q * 8), z, 0, 0, 0);
        acc = __builtin_amdgcn_mfma_f32_16x16x32_bf16(a1, *(const short8*)(wp + 32 + q * 8), acc, 0, 0, 0);
        acc = __builtin_amdgcn_mfma_f32_16x16x32_bf16(a2, *(const short8*)(wp + 64 + q * 8), acc, 0, 0, 0);
        acc = __builtin_amdgcn_mfma_f32_16x16x32_bf16(a3, *(const short8*)(wp + 96 + q * 8), acc, 0, 0, 0);
#pragma unroll
        for (int r = 0; r < 4; ++r) {
          int row = m0 + q * 4 + r, col = nt * 16 + c;
          ef1[row][col] = f2b(silu_f(acc[r] + biasE[2][col]));
        }
      }
    }
    __syncthreads();  // hA dead from here: msgf overlays it
    // S4: msg MLP layer2 (K=64) -> msgf (f32, +bias)
    {
      short8 a0 = *(const short8*)&ef1[m0 + c][q * 8];
      short8 a1 = *(const short8*)&ef1[m0 + c][32 + q * 8];
#pragma unroll
      for (int nt = 0; nt < 4; ++nt) {
        short8 b0 = *(const short8*)&wM2[(nt * 16 + c) * 72 + q * 8];
        short8 b1v = *(const short8*)&wM2[(nt * 16 + c) * 72 + 32 + q * 8];
        f32x4 acc = __builtin_amdgcn_mfma_f32_16x16x32_bf16(a0, b0, z, 0, 0, 0);
        acc = __builtin_amdgcn_mfma_f32_16x16x32_bf16(a1, b1v, acc, 0, 0, 0);
#pragma unroll
        for (int r = 0; r < 4; ++r) {
          int row = m0 + q * 4 + r, col = nt * 16 + c;
          msgf[row][col] = acc[r] + biasE[3][col];
        }
      }
    }
    __syncthreads();
    // Run-reduction: wave w walks rows [16w,16w+16), col = lane.
    // Interior runs plain-store (sole writer), boundary runs atomicAdd.
    {
      int col = lane;
      int r0 = w * 16;
      int cur = tgt_s[r0];
      float run = msgf[r0][col];
      bool lopen = (r0 == 0) ? true : (tgt_s[r0 - 1] == cur);
#pragma unroll
      for (int r2 = 1; r2 < 16; ++r2) {
        int r = r0 + r2;
        int tg = tgt_s[r];
        float v = msgf[r][col];
        if (tg == cur) {
          run += v;
        } else {
          if (cur >= 0) {
            if (lopen) unsafeAtomicAdd(&sums[(long)cur * 64 + col], run);
            else sums[(long)cur * 64 + col] = run;
          }
          cur = tg; run = v; lopen = false;
        }
      }
      bool ropen = (r0 + 16 >= 64) ? true : (tgt_s[r0 + 16] == cur);
      if (cur >= 0) {
        if (lopen || ropen) unsafeAtomicAdd(&sums[(long)cur * 64 + col], run);
        else sums[(long)cur * 64 + col] = run;
      }
    }
    __syncthreads();  // msgf/tgt_s consumed; next tile may overwrite
  }
}

// ---------------------------------------------------------------------------
// Kernel 5: scatter-mean (sum of 8 count shards) + update MLP -> f32 out
// ---------------------------------------------------------------------------
__global__ __launch_bounds__(256) void upd_mlp(
    const float* __restrict__ sums, const int* __restrict__ cnt8,
    const float* __restrict__ fw, float* __restrict__ out, int nrows)
{
  __shared__ float xs[64][68];
  __shared__ float w1s[64][68];
  __shared__ float w2s[64][68];
  __shared__ float b1s[64];
  __shared__ float b2s[64];
  const int t = threadIdx.x;
  const long rbase = (long)blockIdx.x * 64;
  for (int i = t; i < 4096; i += 256) {
    int k = i >> 6, cc = i & 63;
    w1s[k][cc] = fw[FW_UW1 + i];
    w2s[k][cc] = fw[FW_UW2 + i];
  }
  if (t < 64) { b1s[t] = fw[FW_UB1 + t]; b2s[t] = fw[FW_UB2 + t]; }
  {
    int row = t >> 2, ch = t & 3;
    long rg = rbase + row;
    if (rg < nrows) {
      int cn = 0;
#pragma unroll
      for (int cc = 0; cc < 8; ++cc) cn += cnt8[(size_t)cc * nrows + rg];
      float inv = 1.0f / fmaxf((float)cn, 1.0f);
      const float* p = sums + rg * 64 + ch * 16;
#pragma unroll
      for (int m = 0; m < 16; ++m) xs[row][ch * 16 + m] = p[m] * inv;
    } else {
#pragma unroll
      for (int m = 0; m < 16; ++m) xs[row][ch * 16 + m] = 0.f;
    }
  }
  __syncthreads();
  const int r0 = (t >> 4) * 4, c0 = (t & 15) * 4;
  float acc[4][4];
#pragma unroll
  for (int i = 0; i < 4; ++i)
#pragma unroll
    for (int j = 0; j < 4; ++j) acc[i][j] = b1s[c0 + j];
  for (int k = 0; k < 64; ++k) {
    float w0 = w1s[k][c0], w1v = w1s[k][c0 + 1], w2v = w1s[k][c0 + 2], w3v = w1s[k][c0 + 3];
#pragma unroll
    for (int i = 0; i < 4; ++i) {
      float av = xs[r0 + i][k];
      acc[i][0] = fmaf(av, w0, acc[i][0]);
      acc[i][1] = fmaf(av, w1v, acc[i][1]);
      acc[i][2] = fmaf(av, w2v, acc[i][2]);
      acc[i][3] = fmaf(av, w3v, acc[i][3]);
    }
  }
  __syncthreads();
#pragma unroll
  for (int i = 0; i < 4; ++i)
#pragma unroll
    for (int j = 0; j < 4; ++j) xs[r0 + i][c0 + j] = silu_f(acc[i][j]);
  __syncthreads();
  float acc2[4][4];
#pragma unroll
  for (int i = 0; i < 4; ++i)
#pragma unroll
    for (int j = 0; j < 4; ++j) acc2[i][j] = b2s[c0 + j];
  for (int k = 0; k < 64; ++k) {
    float w0 = w2s[k][c0], w1v = w2s[k][c0 + 1], w2v = w2s[k][c0 + 2], w3v = w2s[k][c0 + 3];
#pragma unroll
    for (int i = 0; i < 4; ++i) {
      float av = xs[r0 + i][k];
      acc2[i][0] = fmaf(av, w0, acc2[i][0]);
      acc2[i][1] = fmaf(av, w1v, acc2[i][1]);
      acc2[i][2] = fmaf(av, w2v, acc2[i][2]);
      acc2[i][3] = fmaf(av, w3v, acc2[i][3]);
    }
  }
#pragma unroll
  for (int i = 0; i < 4; ++i) {
    long rg = rbase + r0 + i;
    if (rg < nrows) {
#pragma unroll
      for (int j = 0; j < 4; ++j) out[rg * 64 + c0 + j] = acc2[i][j];
    }
  }
}

// ---------------------------------------------------------------------------
extern "C" void kernel_launch(void* const* d_in, const int* in_sizes, int n_in,
                              void* d_out, int out_size, void* d_ws, size_t ws_size,
                              hipStream_t stream) {
  const int N = in_sizes[1] / 3;
  const int G = in_sizes[2] / 3;
  const long E = (long)in_sizes[4] / 2;
  const int NB2 = (int)((8L * G + 1023) / 1024);   // scan chunks (<=256 for G<=32768)
  const int nodeBlocks = (N + 63) / 64;

  char* ws = (char*)d_ws;
  float* sums = (float*)ws;
  size_t off = (size_t)G * 256;
  int* cnt8 = (int*)(ws + off);     off += (size_t)G * 32;   // 8 shards
  int* cursor8 = (int*)(ws + off);  off += (size_t)G * 32;
  int* bsum = (int*)(ws + off);     off += 1024;
  int* evp = (int*)(ws + off);      off += 256;
  int* flags = (int*)(ws + off);    off += 256;
  unsigned int* pkS = (unsigned int*)(ws + off); off += (size_t)E * 4;
  u16* h_node = (u16*)(ws + off);   off += (size_t)N * 128;
  u16* img = (u16*)(ws + off);      off += (size_t)IMG_TOTAL * 2;
  float* fw = (float*)(ws + off);

  // zero sums + cnt8 (ws poisoned 0xAA before every timed launch)
  hipMemsetAsync(ws, 0, (size_t)G * 288, stream);

  Ptrs a;
  const int map[20] = {0,1,2,3, 5,6,7,8, 9,10,11,12, 13,14,15,16, 17,18,19,20};
  for (int i = 0; i < 20; ++i) { a.p[i] = d_in[map[i]]; a.n[i] = in_sizes[map[i]]; }

  detect_k<<<20, 256, 0, stream>>>(a, flags);
  fused_a<<<HIST_BLOCKS + PREP_BLOCKS + nodeBlocks, 256, 0, stream>>>(
      a, flags, img, fw, (const int*)d_in[4], cnt8, h_node, N, E, G);
  scan_k<<<NB2, 256, 0, stream>>>(cnt8, cursor8, bsum, G);
  scat_k<<<1024, 256, 0, stream>>>((const int*)d_in[4], cursor8, bsum, pkS, evp, E, G, NB2);
  edge_kernel<<<(int)((E + ETILES * 64 - 1) / (ETILES * 64)), 256, 0, stream>>>(
      d_in[1], d_in[2], d_in[3], pkS, evp, h_node, img, fw, flags, sums, G);
  upd_mlp<<<(G + 63) / 64, 256, 0, stream>>>(sums, cnt8, fw, (float*)d_out, G);
}